// Round 3
// baseline (3522.926 us; speedup 1.0000x reference)
//
#include <hip/hip_runtime.h>

#define T_LEN 512
#define HID   40
#define G4    160   // 4*H
#define BT    4     // sequences per block
#define NTH   512   // threads per block (8 waves)
#define ACT_LD 164  // padded act row stride

__device__ __forceinline__ float fast_rcp(float v) { return __builtin_amdgcn_rcpf(v); }

// DPP quad_perm butterfly: xor lane^1 / lane^2 within each quad. Pure VALU.
__device__ __forceinline__ float dpp_add_xor1(float x) {
    return x + __int_as_float(__builtin_amdgcn_update_dpp(
                   0, __float_as_int(x), 0xB1, 0xF, 0xF, true));
}
__device__ __forceinline__ float dpp_add_xor2(float x) {
    return x + __int_as_float(__builtin_amdgcn_update_dpp(
                   0, __float_as_int(x), 0x4E, 0xF, 0xF, true));
}
// xor lane^4 via ds_swizzle BitMode (xor=4, and=0x1F): within 32-lane halves.
__device__ __forceinline__ float swz_add_xor4(float x) {
    int o = __builtin_amdgcn_ds_swizzle(__float_as_int(x), 0x101F);
    return x + __int_as_float(o);
}

// sigmoid, or tanh via tanh(x) = 2*sigmoid(2x)-1
__device__ __forceinline__ float sigm_like(float v, bool isg) {
    float xx = isg ? 2.f * v : v;
    float e  = __expf(-xx);
    float s  = fast_rcp(1.f + e);
    return isg ? 2.f * s - 1.f : s;
}
__device__ __forceinline__ float tanh_fast(float v) {
    float e = __expf(-2.f * v);
    return 2.f * fast_rcp(1.f + e) - 1.f;
}

__device__ __forceinline__ float cell_update(const float* sAct, int b, int u, float& c) {
    float i = sAct[b * ACT_LD + u];
    float f = sAct[b * ACT_LD + 40 + u];
    float g = sAct[b * ACT_LD + 80 + u];
    float o = sAct[b * ACT_LD + 120 + u];
    c = f * c + i * g;
    return o * tanh_fast(c);
}

// Gate matmul: thread (rg, ke) holds 3 gate rows x a K-eighth in VGPRs (78 floats
// total across 3 layers -> fits the 128-VGPR budget, no scratch streaming).
// 3-round reduce (dpp, dpp, ds_swizzle) -> all 8 lanes of the group hold full
// sums; lanes ke<4 own seq b=ke, activate, write LDS act row.
template <int SLICE, int LD>
__device__ __forceinline__ void gate_matmul(const float* __restrict__ Bl,
                                            const float (&W)[3][SLICE],
                                            const float* __restrict__ sBiasL,
                                            const int (&jrow)[3],
                                            float* __restrict__ sAct,
                                            int ke) {
    float acc[3][BT];
#pragma unroll
    for (int jj = 0; jj < 3; ++jj)
#pragma unroll
        for (int b = 0; b < BT; ++b) acc[jj][b] = 0.f;

    const int k0 = ke * SLICE;
#pragma unroll
    for (int b = 0; b < BT; ++b) {
#pragma unroll
        for (int c2 = 0; c2 < SLICE / 2; ++c2) {
            float2 hv = *(const float2*)(Bl + b * LD + k0 + c2 * 2);
#pragma unroll
            for (int jj = 0; jj < 3; ++jj)
                acc[jj][b] += W[jj][2 * c2] * hv.x + W[jj][2 * c2 + 1] * hv.y;
        }
    }

#pragma unroll
    for (int jj = 0; jj < 3; ++jj) {
        float s[BT];
#pragma unroll
        for (int b = 0; b < BT; ++b) {
            float v = acc[jj][b];
            v    = dpp_add_xor1(v);
            v    = dpp_add_xor2(v);
            v    = swz_add_xor4(v);  // all 8 lanes now hold the full K sum
            s[b] = v;
        }
        float lo  = (ke & 1) ? s[1] : s[0];
        float hi  = (ke & 1) ? s[3] : s[2];
        float fin = (ke & 2) ? hi : lo;
        if (ke < 4 && jrow[jj] < G4) {
            bool  isg = (jrow[jj] >= 2 * HID) && (jrow[jj] < 3 * HID);
            float a   = sigm_like(fin + sBiasL[jrow[jj]], isg);
            sAct[ke * ACT_LD + jrow[jj]] = a;
        }
    }
}

__global__ __launch_bounds__(NTH, 4) void lstm_fused(
    const float* __restrict__ x,
    const float* __restrict__ Wih0, const float* __restrict__ Whh0,
    const float* __restrict__ bih0, const float* __restrict__ bhh0,
    const float* __restrict__ Wih1, const float* __restrict__ Whh1,
    const float* __restrict__ bih1, const float* __restrict__ bhh1,
    const float* __restrict__ Wih2, const float* __restrict__ Whh2,
    const float* __restrict__ bih2, const float* __restrict__ bhh2,
    const float* __restrict__ Wout, const float* __restrict__ bout,
    float* __restrict__ out) {
    // B0 = [x(6) | h0(40) | pad2] stride 48; B1 = [h0 | h1]; B2 = [h1 | h2].
    __shared__ __attribute__((aligned(16))) float sB0[BT * 48];
    __shared__ __attribute__((aligned(16))) float sB1[BT * 80];
    __shared__ __attribute__((aligned(16))) float sB2[BT * 80];
    __shared__ __attribute__((aligned(16))) float sAct[BT * ACT_LD];
    __shared__ __attribute__((aligned(16))) float sY[8 * BT * HID];
    __shared__ float sBias0[G4], sBias1[G4], sBias2[G4];

    const int tid  = threadIdx.x;
    const int rg   = tid >> 3;  // row group 0..63 -> rows 3*rg..3*rg+2
    const int ke   = tid & 7;   // K-eighth
    const int seq0 = blockIdx.x * BT;

    // ---- persistent weight registers: 3 rows x K-eighth = 78 floats ----
    float W0[3][6], W1[3][10], W2[3][10];
    int   jrow[3];
#pragma unroll
    for (int jj = 0; jj < 3; ++jj) {
        int j    = rg * 3 + jj;
        jrow[jj] = j;
        if (j < G4) {
#pragma unroll
            for (int k = 0; k < 6; ++k) {
                int   kk = ke * 6 + k;
                float v;
                if (kk < 6)       v = Wih0[j * 6 + kk];
                else if (kk < 46) v = Whh0[j * 40 + (kk - 6)];
                else              v = 0.f;
                W0[jj][k] = v;
            }
#pragma unroll
            for (int k = 0; k < 10; ++k) {
                int kk    = ke * 10 + k;
                W1[jj][k] = (kk < 40) ? Wih1[j * 40 + kk] : Whh1[j * 40 + (kk - 40)];
            }
#pragma unroll
            for (int k = 0; k < 10; ++k) {
                int kk    = ke * 10 + k;
                W2[jj][k] = (kk < 40) ? Wih2[j * 40 + kk] : Whh2[j * 40 + (kk - 40)];
            }
        } else {
#pragma unroll
            for (int k = 0; k < 6; ++k)  W0[jj][k] = 0.f;
#pragma unroll
            for (int k = 0; k < 10; ++k) { W1[jj][k] = 0.f; W2[jj][k] = 0.f; }
        }
    }

    // combined biases -> LDS (saves 9 VGPRs; broadcast read at act time)
    if (tid < G4) {
        sBias0[tid] = bih0[tid] + bhh0[tid];
        sBias1[tid] = bih1[tid] + bhh1[tid];
        sBias2[tid] = bih2[tid] + bhh2[tid];
    }

    // ---- update-phase slots: 160 (b,u) cells on threads 0..159 ----
    const bool upd = (tid < BT * HID);
    const int  b1 = tid / 40, u1 = tid % 40;
    float c0 = 0.f, c1 = 0.f, c2 = 0.f;
    const float wo1   = upd ? Wout[u1] : 0.f;
    const float boutv = bout[0];

    // ---- x prefetch lanes: 4 seq x 6 d = 24 lanes ----
    const int    xb = tid / 6, xd = tid % 6;
    const float* xbase = x + (size_t)seq0 * T_LEN * 6;
    float        xr = 0.f;
    if (tid < 24) xr = xbase[xb * (T_LEN * 6) + 0 * 6 + xd];

    for (int i = tid; i < BT * 48; i += NTH) sB0[i] = 0.f;
    for (int i = tid; i < BT * 80; i += NTH) sB1[i] = 0.f;
    for (int i = tid; i < BT * 80; i += NTH) sB2[i] = 0.f;
    __syncthreads();
    if (tid < 24) {
        sB0[xb * 48 + xd] = xr;
        xr = xbase[xb * (T_LEN * 6) + 1 * 6 + xd];
    }
    __syncthreads();

    for (int t = 0; t < T_LEN; ++t) {
        // A: layer0 gates
        gate_matmul<6, 48>(sB0, W0, sBias0, jrow, sAct, ke);
        __syncthreads();
        // B: layer0 cell update + x staging
        if (upd) {
            float h = cell_update(sAct, b1, u1, c0);
            sB0[b1 * 48 + 6 + u1] = h;
            sB1[b1 * 80 + u1]     = h;
        }
        if (tid < 24 && t + 1 < T_LEN) {
            sB0[xb * 48 + xd] = xr;
            if (t + 2 < T_LEN) xr = xbase[xb * (T_LEN * 6) + (t + 2) * 6 + xd];
        }
        __syncthreads();
        // C: layer1 gates
        gate_matmul<10, 80>(sB1, W1, sBias1, jrow, sAct, ke);
        __syncthreads();
        // D: layer1 cell update
        if (upd) {
            float h = cell_update(sAct, b1, u1, c1);
            sB1[b1 * 80 + 40 + u1] = h;
            sB2[b1 * 80 + u1]      = h;
        }
        __syncthreads();
        // E: layer2 gates
        gate_matmul<10, 80>(sB2, W2, sBias2, jrow, sAct, ke);
        __syncthreads();
        // F: layer2 cell update + y staging
        if (upd) {
            float h = cell_update(sAct, b1, u1, c2);
            sB2[b1 * 80 + 40 + u1]                  = h;
            sY[(t & 7) * (BT * HID) + b1 * 40 + u1] = h * wo1;
        }
        __syncthreads();
        // G: every 8 timesteps, reduce sY -> 32 outputs (8 t x 4 seq)
        if ((t & 7) == 7 && tid < 128) {
            int pr = tid >> 2, kq2 = tid & 3;
            int tt = pr >> 2, bb = pr & 3;
            float s = 0.f;
#pragma unroll
            for (int i2 = 0; i2 < 10; ++i2)
                s += sY[tt * (BT * HID) + bb * 40 + kq2 * 10 + i2];
            s = dpp_add_xor1(s);
            s = dpp_add_xor2(s);
            if (kq2 == 0)
                out[(size_t)(seq0 + bb) * T_LEN + (t - 7) + tt] = s + boutv;
        }
        // no barrier needed: sY slot (t&7) not rewritten until F(t+1), 5 barriers away
    }
}

extern "C" void kernel_launch(void* const* d_in, const int* in_sizes, int n_in,
                              void* d_out, int out_size, void* d_ws, size_t ws_size,
                              hipStream_t stream) {
    const float* x    = (const float*)d_in[0];
    const float* Wih0 = (const float*)d_in[1];
    const float* Whh0 = (const float*)d_in[2];
    const float* bih0 = (const float*)d_in[3];
    const float* bhh0 = (const float*)d_in[4];
    const float* Wih1 = (const float*)d_in[5];
    const float* Whh1 = (const float*)d_in[6];
    const float* bih1 = (const float*)d_in[7];
    const float* bhh1 = (const float*)d_in[8];
    const float* Wih2 = (const float*)d_in[9];
    const float* Whh2 = (const float*)d_in[10];
    const float* bih2 = (const float*)d_in[11];
    const float* bhh2 = (const float*)d_in[12];
    const float* Wout = (const float*)d_in[13];
    const float* bout = (const float*)d_in[14];

    lstm_fused<<<dim3(2048 / BT), dim3(NTH), 0, stream>>>(
        x, Wih0, Whh0, bih0, bhh0, Wih1, Whh1, bih1, bhh1,
        Wih2, Whh2, bih2, bhh2, Wout, bout, (float*)d_out);
}

// Round 4
// 2651.264 us; speedup vs baseline: 1.3288x; 1.3288x over previous
//
#include <hip/hip_runtime.h>

#define T_LEN 512
#define HID   40
#define G4    160      // 4*H
#define BT    8        // sequences per block -> 256 blocks = 1/CU
#define NTH   640      // threads: (j 0..159) x (kq 0..3); tid = j*4+kq
#define ACT_LD 168     // act row stride: 168%32=8 -> write banks {0,8,16,24}, <=2-way

// ---- dynamic LDS map (floats) ----
#define OFF_W4   0                       // 13 chunks * 640 threads * float4
#define OFF_B0   (OFF_W4 + 13 * 640 * 4) // 33280: [x(6)|h0(40)|pad2] * 8, stride 48
#define OFF_B1   (OFF_B0 + BT * 48)      // [h0|h1] * 8, stride 80
#define OFF_B2   (OFF_B1 + BT * 80)      // [h1|h2] * 8, stride 80
#define OFF_ACT  (OFF_B2 + BT * 80)      // 8 * ACT_LD
#define OFF_Y    (OFF_ACT + BT * ACT_LD) // 4-step y staging: 4 * 320
#define OFF_BI0  (OFF_Y + 4 * BT * HID)
#define OFF_BI1  (OFF_BI0 + G4)
#define OFF_BI2  (OFF_BI1 + G4)
#define SMEM_FLOATS (OFF_BI2 + G4)       // 38048 floats = 152192 B
#define SMEM_BYTES  (SMEM_FLOATS * 4)

__device__ __forceinline__ float fast_rcp(float v) { return __builtin_amdgcn_rcpf(v); }

__device__ __forceinline__ float dpp_add_xor1(float x) {
    return x + __int_as_float(__builtin_amdgcn_update_dpp(
                   0, __float_as_int(x), 0xB1, 0xF, 0xF, true));
}
__device__ __forceinline__ float dpp_add_xor2(float x) {
    return x + __int_as_float(__builtin_amdgcn_update_dpp(
                   0, __float_as_int(x), 0x4E, 0xF, 0xF, true));
}

__device__ __forceinline__ float sigm_like(float v, bool isg) {
    float xx = isg ? 2.f * v : v;
    float e  = __expf(-xx);
    float s  = fast_rcp(1.f + e);
    return isg ? 2.f * s - 1.f : s;
}
__device__ __forceinline__ float tanh_fast(float v) {
    float e = __expf(-2.f * v);
    return 2.f * fast_rcp(1.f + e) - 1.f;
}

__device__ __forceinline__ float cell_update(const float* sAct, int b, int u, float& c) {
    float i = sAct[b * ACT_LD + u];
    float f = sAct[b * ACT_LD + 40 + u];
    float g = sAct[b * ACT_LD + 80 + u];
    float o = sAct[b * ACT_LD + 120 + u];
    c = f * c + i * g;
    return o * tanh_fast(c);
}

// One layer's gates. Thread (j,kq) owns gate row j x K-quarter (C float4 chunks).
// Weights re-read from LDS each step (per-thread-contiguous -> conflict-free b128);
// h chunks are quad-uniform multicast reads (4 distinct conflict-free addrs/wave).
// DPP quad reduce -> lane kq holds full sums for b=kq and b=kq+4 -> activate -> sAct.
template <int C, int LD4>
__device__ __forceinline__ void gate_matmul(const float4* __restrict__ B4,
                                            const float4* __restrict__ sW4,
                                            int c0,
                                            const float* __restrict__ sBiasL,
                                            float* __restrict__ sAct,
                                            int tid, int j, int kq, bool isg) {
    float acc[BT];
#pragma unroll
    for (int b = 0; b < BT; ++b) acc[b] = 0.f;

#pragma unroll
    for (int c = 0; c < C; ++c) {
        float4 w4 = sW4[(c0 + c) * NTH + tid];
#pragma unroll
        for (int b = 0; b < BT; ++b) {
            float4 h4 = B4[b * LD4 + kq * C + c];
            acc[b] += w4.x * h4.x;
            acc[b] += w4.y * h4.y;
            acc[b] += w4.z * h4.z;
            acc[b] += w4.w * h4.w;
        }
    }

    float s[BT];
#pragma unroll
    for (int b = 0; b < BT; ++b) {
        float v = acc[b];
        v    = dpp_add_xor1(v);
        v    = dpp_add_xor2(v);  // all 4 quad lanes now hold full sum for b
        s[b] = v;
    }
    // lane kq keeps b=kq and b=kq+4
    float lo0 = (kq & 1) ? s[1] : s[0];
    float hi0 = (kq & 1) ? s[3] : s[2];
    float f0  = (kq & 2) ? hi0 : lo0;
    float lo1 = (kq & 1) ? s[5] : s[4];
    float hi1 = (kq & 1) ? s[7] : s[6];
    float f1  = (kq & 2) ? hi1 : lo1;

    float bia = sBiasL[j];  // quad-uniform broadcast
    float a0  = sigm_like(f0 + bia, isg);
    float a1  = sigm_like(f1 + bia, isg);
    sAct[kq * ACT_LD + j]       = a0;
    sAct[(kq + 4) * ACT_LD + j] = a1;
}

__global__ __launch_bounds__(NTH) void lstm_fused(
    const float* __restrict__ x,
    const float* __restrict__ Wih0, const float* __restrict__ Whh0,
    const float* __restrict__ bih0, const float* __restrict__ bhh0,
    const float* __restrict__ Wih1, const float* __restrict__ Whh1,
    const float* __restrict__ bih1, const float* __restrict__ bhh1,
    const float* __restrict__ Wih2, const float* __restrict__ Whh2,
    const float* __restrict__ bih2, const float* __restrict__ bhh2,
    const float* __restrict__ Wout, const float* __restrict__ bout,
    float* __restrict__ out) {
    extern __shared__ __attribute__((aligned(16))) float smem[];
    float4*      sW4   = (float4*)(smem + OFF_W4);
    float*       sB0   = smem + OFF_B0;
    float*       sB1   = smem + OFF_B1;
    float*       sB2   = smem + OFF_B2;
    float*       sAct  = smem + OFF_ACT;
    float*       sY    = smem + OFF_Y;
    float*       sBi0  = smem + OFF_BI0;
    float*       sBi1  = smem + OFF_BI1;
    float*       sBi2  = smem + OFF_BI2;

    const int tid  = threadIdx.x;
    const int j    = tid >> 2;
    const int kq   = tid & 3;
    const bool isg = (j >= 2 * HID) && (j < 3 * HID);
    const int seq0 = blockIdx.x * BT;

    // ---- one-time: gather this thread's 13 weight chunks into packed LDS ----
    {
        float v[4];
#pragma unroll
        for (int c = 0; c < 3; ++c) {  // L0: K-compound [Wih0(6)|Whh0(40)|pad2], slice 12
#pragma unroll
            for (int e = 0; e < 4; ++e) {
                int kk = kq * 12 + c * 4 + e;
                if (kk < 6)       v[e] = Wih0[j * 6 + kk];
                else if (kk < 46) v[e] = Whh0[j * 40 + (kk - 6)];
                else              v[e] = 0.f;
            }
            sW4[c * NTH + tid] = make_float4(v[0], v[1], v[2], v[3]);
        }
#pragma unroll
        for (int c = 0; c < 5; ++c) {  // L1: [Wih1(40)|Whh1(40)], slice 20
#pragma unroll
            for (int e = 0; e < 4; ++e) {
                int kk = kq * 20 + c * 4 + e;
                v[e]   = (kk < 40) ? Wih1[j * 40 + kk] : Whh1[j * 40 + (kk - 40)];
            }
            sW4[(3 + c) * NTH + tid] = make_float4(v[0], v[1], v[2], v[3]);
        }
#pragma unroll
        for (int c = 0; c < 5; ++c) {  // L2
#pragma unroll
            for (int e = 0; e < 4; ++e) {
                int kk = kq * 20 + c * 4 + e;
                v[e]   = (kk < 40) ? Wih2[j * 40 + kk] : Whh2[j * 40 + (kk - 40)];
            }
            sW4[(8 + c) * NTH + tid] = make_float4(v[0], v[1], v[2], v[3]);
        }
    }
    if (tid < G4) {
        sBi0[tid] = bih0[tid] + bhh0[tid];
        sBi1[tid] = bih1[tid] + bhh1[tid];
        sBi2[tid] = bih2[tid] + bhh2[tid];
    }

    // ---- update-phase slots: 320 (b,u) cells on threads 0..319 ----
    const bool upd = (tid < BT * HID);
    const int  b1 = tid / 40, u1 = tid % 40;
    float c0s = 0.f, c1s = 0.f, c2s = 0.f;
    const float wo1   = upd ? Wout[u1] : 0.f;
    const float boutv = bout[0];

    // ---- x prefetch lanes: 8 seq x 6 d = 48 lanes ----
    const int    xb = tid / 6, xd = tid % 6;
    const float* xbase = x + (size_t)seq0 * T_LEN * 6;
    float        xr = 0.f;
    if (tid < 48) xr = xbase[xb * (T_LEN * 6) + 0 * 6 + xd];

    for (int i = tid; i < BT * 48; i += NTH) sB0[i] = 0.f;
    for (int i = tid; i < BT * 80; i += NTH) sB1[i] = 0.f;
    for (int i = tid; i < BT * 80; i += NTH) sB2[i] = 0.f;
    __syncthreads();
    if (tid < 48) {
        sB0[xb * 48 + xd] = xr;
        xr = xbase[xb * (T_LEN * 6) + 1 * 6 + xd];
    }
    __syncthreads();

    for (int t = 0; t < T_LEN; ++t) {
        // A: layer0 gates
        gate_matmul<3, 12>((const float4*)sB0, sW4, 0, sBi0, sAct, tid, j, kq, isg);
        __syncthreads();
        // B: layer0 cell update + x staging
        if (upd) {
            float h = cell_update(sAct, b1, u1, c0s);
            sB0[b1 * 48 + 6 + u1] = h;
            sB1[b1 * 80 + u1]     = h;
        }
        if (tid < 48 && t + 1 < T_LEN) {
            sB0[xb * 48 + xd] = xr;
            if (t + 2 < T_LEN) xr = xbase[xb * (T_LEN * 6) + (t + 2) * 6 + xd];
        }
        __syncthreads();
        // C: layer1 gates
        gate_matmul<5, 20>((const float4*)sB1, sW4, 3, sBi1, sAct, tid, j, kq, isg);
        __syncthreads();
        // D: layer1 cell update
        if (upd) {
            float h = cell_update(sAct, b1, u1, c1s);
            sB1[b1 * 80 + 40 + u1] = h;
            sB2[b1 * 80 + u1]      = h;
        }
        __syncthreads();
        // E: layer2 gates
        gate_matmul<5, 20>((const float4*)sB2, sW4, 8, sBi2, sAct, tid, j, kq, isg);
        __syncthreads();
        // F: layer2 cell update + y staging
        if (upd) {
            float h = cell_update(sAct, b1, u1, c2s);
            sB2[b1 * 80 + 40 + u1]                  = h;
            sY[(t & 3) * (BT * HID) + b1 * 40 + u1] = h * wo1;
        }
        __syncthreads();
        // G: every 4 timesteps, reduce sY -> 32 outputs (4 t x 8 seq)
        if ((t & 3) == 3 && tid < 128) {
            int pr = tid >> 2, kq2 = tid & 3;
            int tt = pr >> 3, bb = pr & 7;
            float s = 0.f;
#pragma unroll
            for (int i2 = 0; i2 < 10; ++i2)
                s += sY[tt * (BT * HID) + bb * 40 + kq2 * 10 + i2];
            s = dpp_add_xor1(s);
            s = dpp_add_xor2(s);
            if (kq2 == 0)
                out[(size_t)(seq0 + bb) * T_LEN + (t - 3) + tt] = s + boutv;
        }
        // safe: sY slot (t&3) not rewritten until F(t+1), 5 barriers after G
    }
}

extern "C" void kernel_launch(void* const* d_in, const int* in_sizes, int n_in,
                              void* d_out, int out_size, void* d_ws, size_t ws_size,
                              hipStream_t stream) {
    const float* x    = (const float*)d_in[0];
    const float* Wih0 = (const float*)d_in[1];
    const float* Whh0 = (const float*)d_in[2];
    const float* bih0 = (const float*)d_in[3];
    const float* bhh0 = (const float*)d_in[4];
    const float* Wih1 = (const float*)d_in[5];
    const float* Whh1 = (const float*)d_in[6];
    const float* bih1 = (const float*)d_in[7];
    const float* bhh1 = (const float*)d_in[8];
    const float* Wih2 = (const float*)d_in[9];
    const float* Whh2 = (const float*)d_in[10];
    const float* bih2 = (const float*)d_in[11];
    const float* bhh2 = (const float*)d_in[12];
    const float* Wout = (const float*)d_in[13];
    const float* bout = (const float*)d_in[14];

    // allow >64 KB dynamic LDS (152 KB of 160 KB/CU); idempotent, capture-safe
    hipFuncSetAttribute((const void*)lstm_fused,
                        hipFuncAttributeMaxDynamicSharedMemorySize, SMEM_BYTES);

    lstm_fused<<<dim3(2048 / BT), dim3(NTH), SMEM_BYTES, stream>>>(
        x, Wih0, Whh0, bih0, bhh0, Wih1, Whh1, bih1, bhh1,
        Wih2, Whh2, bih2, bhh2, Wout, bout, (float*)d_out);
}

// Round 5
// 1053.969 us; speedup vs baseline: 3.3425x; 2.5155x over previous
//
#include <hip/hip_runtime.h>

#define T_LEN 512
#define HID   40
#define G4    160
#define BT    8        // sequences per block -> grid 256 = 1 block/CU
#define NTH   640      // 10 waves = 10 M-tiles of 16 gate rows
#define ACT_LD 164
#define R16   16       // padded N rows of B-fragment buffers
#define K0P   72       // L0 K-pad (k 0..63 used; weights 0 for k>=46)
#define K12P  104      // L1/L2 K-pad (k 0..95 used; weights 0 for k>=80)

typedef _Float16 f16x8 __attribute__((ext_vector_type(8)));
typedef float    f32x4 __attribute__((ext_vector_type(4)));

__device__ __forceinline__ float fast_rcp(float v) { return __builtin_amdgcn_rcpf(v); }

__device__ __forceinline__ float dpp_add_xor1(float x) {
    return x + __int_as_float(__builtin_amdgcn_update_dpp(
                   0, __float_as_int(x), 0xB1, 0xF, 0xF, true));
}
__device__ __forceinline__ float dpp_add_xor2(float x) {
    return x + __int_as_float(__builtin_amdgcn_update_dpp(
                   0, __float_as_int(x), 0x4E, 0xF, 0xF, true));
}

__device__ __forceinline__ float sigm_like(float v, bool isg) {
    float xx = isg ? 2.f * v : v;
    float e  = __expf(-xx);
    float s  = fast_rcp(1.f + e);
    return isg ? 2.f * s - 1.f : s;
}
__device__ __forceinline__ float tanh_fast(float v) {
    float e = __expf(-2.f * v);
    return 2.f * fast_rcp(1.f + e) - 1.f;
}

__device__ __forceinline__ float cell_update(const float* sAct, int b, int u, float& c) {
    float i = sAct[b * ACT_LD + u];
    float f = sAct[b * ACT_LD + 40 + u];
    float g = sAct[b * ACT_LD + 80 + u];
    float o = sAct[b * ACT_LD + 120 + u];
    c = f * c + i * g;
    return o * tanh_fast(c);
}

// write h as split fp16 pair
__device__ __forceinline__ void wr_h(_Float16* Bh, _Float16* Bl, int idx, float h) {
    _Float16 hh = (_Float16)h;
    Bh[idx]     = hh;
    Bl[idx]     = (_Float16)(h - (float)hh);
}

// One gate GEMM on the matrix pipe: KS K-steps, 3 split-precision terms each.
// A-frags in registers (weights, time-invariant); B-frags from LDS.
template <int KS, int KPAD>
__device__ __forceinline__ f32x4 gemm_mfma(const _Float16* __restrict__ Bh,
                                           const _Float16* __restrict__ Bl,
                                           const f16x8 (&Ah)[KS], const f16x8 (&Al)[KS],
                                           f32x4 acc, int n, int quad) {
#pragma unroll
    for (int s = 0; s < KS; ++s) {
        f16x8 bh = *(const f16x8*)(Bh + n * KPAD + s * 32 + quad * 8);
        f16x8 bl = *(const f16x8*)(Bl + n * KPAD + s * 32 + quad * 8);
        acc = __builtin_amdgcn_mfma_f32_16x16x32_f16(Ah[s], bh, acc, 0, 0, 0);
        acc = __builtin_amdgcn_mfma_f32_16x16x32_f16(Ah[s], bl, acc, 0, 0, 0);
        acc = __builtin_amdgcn_mfma_f32_16x16x32_f16(Al[s], bh, acc, 0, 0, 0);
    }
    return acc;
}

__global__ __launch_bounds__(NTH, 2) void lstm_fused(
    const float* __restrict__ x,
    const float* __restrict__ Wih0, const float* __restrict__ Whh0,
    const float* __restrict__ bih0, const float* __restrict__ bhh0,
    const float* __restrict__ Wih1, const float* __restrict__ Whh1,
    const float* __restrict__ bih1, const float* __restrict__ bhh1,
    const float* __restrict__ Wih2, const float* __restrict__ Whh2,
    const float* __restrict__ bih2, const float* __restrict__ bhh2,
    const float* __restrict__ Wout, const float* __restrict__ bout,
    float* __restrict__ out) {
    // B-fragment buffers: [n=16][Kpad] fp16, hi/lo. L0 Z=[x(6)|h0(40)]; L1=[h0|h1]; L2=[h1|h2].
    __shared__ __attribute__((aligned(16))) _Float16 sB0h[R16 * K0P],  sB0l[R16 * K0P];
    __shared__ __attribute__((aligned(16))) _Float16 sB1h[R16 * K12P], sB1l[R16 * K12P];
    __shared__ __attribute__((aligned(16))) _Float16 sB2h[R16 * K12P], sB2l[R16 * K12P];
    __shared__ __attribute__((aligned(16))) float    sAct[BT * ACT_LD];
    __shared__ __attribute__((aligned(16))) float    sY[4 * BT * HID];

    const int tid  = threadIdx.x;
    const int lane = tid & 63;
    const int widx = tid >> 6;        // wave = M-tile (rows widx*16 .. +15)
    const int n    = lane & 15;       // B col / D col (seq b when n<8)
    const int quad = lane >> 4;
    const int m    = widx * 16 + n;   // A row (gate j) this lane supplies
    const int j0   = widx * 16 + quad * 4;  // D rows j0..j0+3 in acc[0..3]
    const int seq0 = blockIdx.x * BT;

    // ---- one-time: A-fragments (weights, split fp16) into registers ----
    f16x8 A0h[2], A0l[2], A1h[3], A1l[3], A2h[3], A2l[3];
#pragma unroll
    for (int s = 0; s < 2; ++s)
#pragma unroll
        for (int jj = 0; jj < 8; ++jj) {
            int   k = s * 32 + quad * 8 + jj;
            float w = (k < 6) ? Wih0[m * 6 + k] : (k < 46) ? Whh0[m * 40 + (k - 6)] : 0.f;
            _Float16 h = (_Float16)w;
            A0h[s][jj] = h;
            A0l[s][jj] = (_Float16)(w - (float)h);
        }
#pragma unroll
    for (int s = 0; s < 3; ++s)
#pragma unroll
        for (int jj = 0; jj < 8; ++jj) {
            int   k  = s * 32 + quad * 8 + jj;
            float w1 = (k < 40) ? Wih1[m * 40 + k] : (k < 80) ? Whh1[m * 40 + (k - 40)] : 0.f;
            float w2 = (k < 40) ? Wih2[m * 40 + k] : (k < 80) ? Whh2[m * 40 + (k - 40)] : 0.f;
            _Float16 h1 = (_Float16)w1, h2 = (_Float16)w2;
            A1h[s][jj] = h1; A1l[s][jj] = (_Float16)(w1 - (float)h1);
            A2h[s][jj] = h2; A2l[s][jj] = (_Float16)(w2 - (float)h2);
        }

    // biases pre-added via accumulator init; one per D row r
    f32x4 bia0, bia1, bia2;
    bool  isgr[4];
#pragma unroll
    for (int r = 0; r < 4; ++r) {
        int jr  = j0 + r;
        bia0[r] = bih0[jr] + bhh0[jr];
        bia1[r] = bih1[jr] + bhh1[jr];
        bia2[r] = bih2[jr] + bhh2[jr];
        isgr[r] = (jr >= 2 * HID) && (jr < 3 * HID);
    }

    // ---- update-phase slots: 320 (b,u) cells on threads 0..319 ----
    const bool upd = (tid < BT * HID);
    const int  b1 = tid / 40, u1 = tid % 40;
    float c0 = 0.f, c1 = 0.f, c2 = 0.f;
    const float wo1   = upd ? Wout[u1] : 0.f;
    const float boutv = bout[0];

    // ---- x prefetch lanes: 8 seq x 6 d ----
    const int    xb = tid / 6, xd = tid % 6;
    const float* xbase = x + (size_t)seq0 * T_LEN * 6;
    float        xr = 0.f;
    if (tid < 48) xr = xbase[xb * (T_LEN * 6) + 0 * 6 + xd];

    // zero all B-fragment buffers (pads + rows n>=8 stay zero forever)
    for (int i = tid; i < R16 * K0P; i += NTH)  { sB0h[i] = (_Float16)0.f; sB0l[i] = (_Float16)0.f; }
    for (int i = tid; i < R16 * K12P; i += NTH) { sB1h[i] = (_Float16)0.f; sB1l[i] = (_Float16)0.f;
                                                  sB2h[i] = (_Float16)0.f; sB2l[i] = (_Float16)0.f; }
    __syncthreads();
    if (tid < 48) {
        wr_h(sB0h, sB0l, xb * K0P + xd, xr);           // x(0)
        xr = xbase[xb * (T_LEN * 6) + 1 * 6 + xd];     // prefetch x(1)
    }
    __syncthreads();

    for (int t = 0; t < T_LEN; ++t) {
        // ---- L0 gates (MFMA) ----
        {
            f32x4 acc = gemm_mfma<2, K0P>(sB0h, sB0l, A0h, A0l, bia0, n, quad);
            if (n < 8) {
                float4 st;
                st.x = sigm_like(acc[0], isgr[0]);
                st.y = sigm_like(acc[1], isgr[1]);
                st.z = sigm_like(acc[2], isgr[2]);
                st.w = sigm_like(acc[3], isgr[3]);
                *(float4*)&sAct[n * ACT_LD + j0] = st;
            }
        }
        __syncthreads();
        // ---- L0 cell update + x staging ----
        if (upd) {
            float h = cell_update(sAct, b1, u1, c0);
            wr_h(sB0h, sB0l, b1 * K0P + 6 + u1, h);
            wr_h(sB1h, sB1l, b1 * K12P + u1, h);
        }
        if (tid < 48 && t + 1 < T_LEN) {
            wr_h(sB0h, sB0l, xb * K0P + xd, xr);
            if (t + 2 < T_LEN) xr = xbase[xb * (T_LEN * 6) + (t + 2) * 6 + xd];
        }
        __syncthreads();
        // ---- L1 gates (MFMA) ----
        {
            f32x4 acc = gemm_mfma<3, K12P>(sB1h, sB1l, A1h, A1l, bia1, n, quad);
            if (n < 8) {
                float4 st;
                st.x = sigm_like(acc[0], isgr[0]);
                st.y = sigm_like(acc[1], isgr[1]);
                st.z = sigm_like(acc[2], isgr[2]);
                st.w = sigm_like(acc[3], isgr[3]);
                *(float4*)&sAct[n * ACT_LD + j0] = st;
            }
        }
        __syncthreads();
        // ---- L1 cell update ----
        if (upd) {
            float h = cell_update(sAct, b1, u1, c1);
            wr_h(sB1h, sB1l, b1 * K12P + 40 + u1, h);
            wr_h(sB2h, sB2l, b1 * K12P + u1, h);
        }
        __syncthreads();
        // ---- L2 gates (MFMA) ----
        {
            f32x4 acc = gemm_mfma<3, K12P>(sB2h, sB2l, A2h, A2l, bia2, n, quad);
            if (n < 8) {
                float4 st;
                st.x = sigm_like(acc[0], isgr[0]);
                st.y = sigm_like(acc[1], isgr[1]);
                st.z = sigm_like(acc[2], isgr[2]);
                st.w = sigm_like(acc[3], isgr[3]);
                *(float4*)&sAct[n * ACT_LD + j0] = st;
            }
        }
        __syncthreads();
        // ---- L2 cell update + y staging ----
        if (upd) {
            float h = cell_update(sAct, b1, u1, c2);
            wr_h(sB2h, sB2l, b1 * K12P + 40 + u1, h);
            sY[(t & 3) * (BT * HID) + b1 * 40 + u1] = h * wo1;
        }
        __syncthreads();
        // ---- every 4 steps: reduce sY -> 32 outputs (4 t x 8 seq) ----
        if ((t & 3) == 3 && tid < 128) {
            int pr = tid >> 2, kq2 = tid & 3;
            int tt = pr >> 3, bb = pr & 7;
            float s = 0.f;
#pragma unroll
            for (int i2 = 0; i2 < 10; ++i2)
                s += sY[tt * (BT * HID) + bb * 40 + kq2 * 10 + i2];
            s = dpp_add_xor1(s);
            s = dpp_add_xor2(s);
            if (kq2 == 0)
                out[(size_t)(seq0 + bb) * T_LEN + (t - 3) + tt] = s + boutv;
        }
        // safe: sY slot (t&3) rewritten only at next step's L2-update, 5 barriers later
    }
}

extern "C" void kernel_launch(void* const* d_in, const int* in_sizes, int n_in,
                              void* d_out, int out_size, void* d_ws, size_t ws_size,
                              hipStream_t stream) {
    const float* x    = (const float*)d_in[0];
    const float* Wih0 = (const float*)d_in[1];
    const float* Whh0 = (const float*)d_in[2];
    const float* bih0 = (const float*)d_in[3];
    const float* bhh0 = (const float*)d_in[4];
    const float* Wih1 = (const float*)d_in[5];
    const float* Whh1 = (const float*)d_in[6];
    const float* bih1 = (const float*)d_in[7];
    const float* bhh1 = (const float*)d_in[8];
    const float* Wih2 = (const float*)d_in[9];
    const float* Whh2 = (const float*)d_in[10];
    const float* bih2 = (const float*)d_in[11];
    const float* bhh2 = (const float*)d_in[12];
    const float* Wout = (const float*)d_in[13];
    const float* bout = (const float*)d_in[14];

    lstm_fused<<<dim3(2048 / BT), dim3(NTH), 0, stream>>>(
        x, Wih0, Whh0, bih0, bhh0, Wih1, Whh1, bih1, bhh1,
        Wih2, Whh2, bih2, bhh2, Wout, bout, (float*)d_out);
}

// Round 6
// 800.104 us; speedup vs baseline: 4.4031x; 1.3173x over previous
//
#include <hip/hip_runtime.h>

#define T_LEN 512
#define HID   40
#define BT    8        // sequences per block -> grid 256 = 1 block/CU
#define NTH   640      // 10 waves; wave w owns units u = 4w..4w+3 (all 4 gates)

typedef _Float16 f16x8 __attribute__((ext_vector_type(8)));
typedef float    f32x4 __attribute__((ext_vector_type(4)));

// B-fragment LDS: chunked lane-linear layout, parity double-buffered.
// Region offsets in fp16 units within one parity bank:
#define O_L0H 0        // L0 (K-pad 64): 2 K-steps * 64 chunks * 8 = 1024
#define O_L0L 1024
#define O_L1H 2048     // L1 (K-pad 96): 3 * 64 * 8 = 1536
#define O_L1L 3584
#define O_L2H 5120
#define O_L2L 6656
#define PARSZ 8192     // fp16 per parity bank (16 KB)

__device__ __forceinline__ float fast_rcp(float v) { return __builtin_amdgcn_rcpf(v); }
__device__ __forceinline__ float sigm(float v) { return fast_rcp(1.f + __expf(-v)); }
__device__ __forceinline__ float tanh_fast(float v) {
    return 2.f * fast_rcp(1.f + __expf(-2.f * v)) - 1.f;
}

__device__ __forceinline__ float dpp_add_xor1(float x) {
    return x + __int_as_float(__builtin_amdgcn_update_dpp(
                   0, __float_as_int(x), 0xB1, 0xF, 0xF, true));
}
__device__ __forceinline__ float dpp_add_xor2(float x) {
    return x + __int_as_float(__builtin_amdgcn_update_dpp(
                   0, __float_as_int(x), 0x4E, 0xF, 0xF, true));
}

// element index inside a layer region for (kpos, col n):
// chunk = s*64 + qw*16 + n, elem j  (s=kpos/32, qw=(kpos%32)/8, j=kpos%8)
__device__ __forceinline__ int bidx(int kpos, int n) {
    return (((kpos >> 5) * 64) + (((kpos >> 3) & 3) * 16) + n) * 8 + (kpos & 7);
}
__device__ __forceinline__ void wr_split(_Float16* h, _Float16* l, int idx, float v) {
    _Float16 hi = (_Float16)v;
    h[idx]      = hi;
    l[idx]      = (_Float16)(v - (float)hi);
}

// KS K-steps, 3 split-precision MFMA terms each; B reads are lane-linear 16B
// (conflict-free ds_read_b128). A-frags register/AGPR-resident.
template <int KS>
__device__ __forceinline__ f32x4 gemm3(const _Float16* __restrict__ bh_,
                                       const _Float16* __restrict__ bl_,
                                       const f16x8 (&Ah)[KS], const f16x8 (&Al)[KS],
                                       f32x4 acc, int lane) {
#pragma unroll
    for (int s = 0; s < KS; ++s) {
        f16x8 bh = *(const f16x8*)(bh_ + (s * 64 + lane) * 8);
        f16x8 bl = *(const f16x8*)(bl_ + (s * 64 + lane) * 8);
        acc = __builtin_amdgcn_mfma_f32_16x16x32_f16(Ah[s], bh, acc, 0, 0, 0);
        acc = __builtin_amdgcn_mfma_f32_16x16x32_f16(Ah[s], bl, acc, 0, 0, 0);
        acc = __builtin_amdgcn_mfma_f32_16x16x32_f16(Al[s], bh, acc, 0, 0, 0);
    }
    return acc;
}

__global__ __launch_bounds__(NTH, 2) void lstm_fused(
    const float* __restrict__ x,
    const float* __restrict__ Wih0, const float* __restrict__ Whh0,
    const float* __restrict__ bih0, const float* __restrict__ bhh0,
    const float* __restrict__ Wih1, const float* __restrict__ Whh1,
    const float* __restrict__ bih1, const float* __restrict__ bhh1,
    const float* __restrict__ Wih2, const float* __restrict__ Whh2,
    const float* __restrict__ bih2, const float* __restrict__ bhh2,
    const float* __restrict__ Wout, const float* __restrict__ bout,
    float* __restrict__ out) {
    __shared__ __attribute__((aligned(16))) _Float16 sBF[2 * PARSZ];   // 32 KB
    __shared__ __attribute__((aligned(16))) float    sY[4 * HID * BT]; // 5 KB

    const int tid  = threadIdx.x;
    const int lane = tid & 63;
    const int w    = tid >> 6;        // wave id = u-tile
    const int n    = lane & 15;       // B/D column (seq b when n<8)
    const int quad = lane >> 4;
    const int u    = w * 4 + quad;    // hidden unit this lane owns (cell update)
    const int seq0 = blockIdx.x * BT;

    // ---- A-fragments: gate-permuted rows, split fp16, built once ----
    // tile row r -> gate j = (r%4)*40 + w*4 + r/4 ; lane supplies A row n, k=quad*8+jj
    const int ja = (n & 3) * 40 + w * 4 + (n >> 2);
    f16x8 A0h[2], A0l[2], A1h[3], A1l[3], A2h[3], A2l[3];
#pragma unroll
    for (int s = 0; s < 2; ++s)
#pragma unroll
        for (int jj = 0; jj < 8; ++jj) {
            int   k = s * 32 + quad * 8 + jj;
            float v = (k < 6) ? Wih0[ja * 6 + k] : (k < 46) ? Whh0[ja * 40 + (k - 6)] : 0.f;
            _Float16 hi = (_Float16)v;
            A0h[s][jj] = hi;
            A0l[s][jj] = (_Float16)(v - (float)hi);
        }
#pragma unroll
    for (int s = 0; s < 3; ++s)
#pragma unroll
        for (int jj = 0; jj < 8; ++jj) {
            int   k  = s * 32 + quad * 8 + jj;
            float v1 = (k < 40) ? Wih1[ja * 40 + k] : (k < 80) ? Whh1[ja * 40 + (k - 40)] : 0.f;
            float v2 = (k < 40) ? Wih2[ja * 40 + k] : (k < 80) ? Whh2[ja * 40 + (k - 40)] : 0.f;
            _Float16 h1 = (_Float16)v1, h2 = (_Float16)v2;
            A1h[s][jj] = h1; A1l[s][jj] = (_Float16)(v1 - (float)h1);
            A2h[s][jj] = h2; A2l[s][jj] = (_Float16)(v2 - (float)h2);
        }

    // biases in accumulator-init; D row quad*4+reg = gate reg of unit u
    f32x4 bia0, bia1, bia2;
#pragma unroll
    for (int reg = 0; reg < 4; ++reg) {
        int jr    = reg * 40 + u;
        bia0[reg] = bih0[jr] + bhh0[jr];
        bia1[reg] = bih1[jr] + bhh1[jr];
        bia2[reg] = bih2[jr] + bhh2[jr];
    }
    const float wov   = Wout[u];
    const float boutv = bout[0];

    float c0 = 0.f, c1 = 0.f, c2 = 0.f;  // cell states for (b=n, u), lanes n<8

    // ---- x prefetch lanes: 8 seq x 6 d ----
    const int    xb = tid / 6, xd = tid % 6;
    const float* xbase = x + (size_t)seq0 * T_LEN * 6;
    float        xr = 0.f;
    if (tid < 48) xr = xbase[xb * (T_LEN * 6) + 0 * 6 + xd];

    // zero both parity banks (pads + cols n>=8 stay zero forever)
    for (int i = tid; i < 2 * PARSZ / 8; i += NTH)
        *(float4*)&sBF[i * 8] = make_float4(0.f, 0.f, 0.f, 0.f);
    __syncthreads();
    if (tid < 48) {
        wr_split(sBF + O_L0H, sBF + O_L0L, bidx(xd, xb), xr);  // x(0) -> parity 0
        xr = xbase[xb * (T_LEN * 6) + 1 * 6 + xd];             // prefetch x(1)
    }
    __syncthreads();

    for (int t = 0; t < T_LEN; ++t) {
        const int po = (t & 1) * PARSZ;        // read parity
        const int qo = ((t & 1) ^ 1) * PARSZ;  // write parity (next step)

        // ---- phase A: L0 gates + in-lane cell update ----
        {
            f32x4 acc = gemm3<2>(sBF + po + O_L0H, sBF + po + O_L0L, A0h, A0l, bia0, lane);
            float ii = sigm(acc[0]), ff = sigm(acc[1]);
            float gg = tanh_fast(acc[2]), oo = sigm(acc[3]);
            c0       = ff * c0 + ii * gg;
            float h  = oo * tanh_fast(c0);
            if (n < 8) {
                wr_split(sBF + qo + O_L0H, sBF + qo + O_L0L, bidx(6 + u, n), h);
                wr_split(sBF + po + O_L1H, sBF + po + O_L1L, bidx(u, n), h);
            }
        }
        __syncthreads();
        // ---- phase B: L1 gates + update; x(t+1) staging ----
        {
            f32x4 acc = gemm3<3>(sBF + po + O_L1H, sBF + po + O_L1L, A1h, A1l, bia1, lane);
            float ii = sigm(acc[0]), ff = sigm(acc[1]);
            float gg = tanh_fast(acc[2]), oo = sigm(acc[3]);
            c1       = ff * c1 + ii * gg;
            float h  = oo * tanh_fast(c1);
            if (n < 8) {
                wr_split(sBF + qo + O_L1H, sBF + qo + O_L1L, bidx(40 + u, n), h);
                wr_split(sBF + po + O_L2H, sBF + po + O_L2L, bidx(u, n), h);
            }
            if (tid < 48 && t + 1 < T_LEN) {
                wr_split(sBF + qo + O_L0H, sBF + qo + O_L0L, bidx(xd, xb), xr);
                if (t + 2 < T_LEN) xr = xbase[xb * (T_LEN * 6) + (t + 2) * 6 + xd];
            }
        }
        __syncthreads();
        // ---- phase C: L2 gates + update + y staging ----
        {
            f32x4 acc = gemm3<3>(sBF + po + O_L2H, sBF + po + O_L2L, A2h, A2l, bia2, lane);
            float ii = sigm(acc[0]), ff = sigm(acc[1]);
            float gg = tanh_fast(acc[2]), oo = sigm(acc[3]);
            c2       = ff * c2 + ii * gg;
            float h  = oo * tanh_fast(c2);
            if (n < 8) {
                wr_split(sBF + qo + O_L2H, sBF + qo + O_L2L, bidx(40 + u, n), h);
                sY[(t & 3) * (HID * BT) + u * BT + n] = h * wov;
            }
        }
        __syncthreads();
        // ---- every 4 steps: reduce sY -> 32 outputs (4 t x 8 seq) ----
        if ((t & 3) == 3 && tid < 128) {
            int o = tid >> 2, part = tid & 3;
            int tt = o >> 3, bb = o & 7;
            float s = 0.f;
#pragma unroll
            for (int i2 = 0; i2 < 10; ++i2)
                s += sY[tt * (HID * BT) + (part * 10 + i2) * BT + bb];
            s = dpp_add_xor1(s);
            s = dpp_add_xor2(s);
            if (part == 0)
                out[(size_t)(seq0 + bb) * T_LEN + (t - 3) + tt] = s + boutv;
        }
        // safe: sY slot rewritten 2 barriers after this read (phase C of t+1)
    }
}

extern "C" void kernel_launch(void* const* d_in, const int* in_sizes, int n_in,
                              void* d_out, int out_size, void* d_ws, size_t ws_size,
                              hipStream_t stream) {
    const float* x    = (const float*)d_in[0];
    const float* Wih0 = (const float*)d_in[1];
    const float* Whh0 = (const float*)d_in[2];
    const float* bih0 = (const float*)d_in[3];
    const float* bhh0 = (const float*)d_in[4];
    const float* Wih1 = (const float*)d_in[5];
    const float* Whh1 = (const float*)d_in[6];
    const float* bih1 = (const float*)d_in[7];
    const float* bhh1 = (const float*)d_in[8];
    const float* Wih2 = (const float*)d_in[9];
    const float* Whh2 = (const float*)d_in[10];
    const float* bih2 = (const float*)d_in[11];
    const float* bhh2 = (const float*)d_in[12];
    const float* Wout = (const float*)d_in[13];
    const float* bout = (const float*)d_in[14];

    lstm_fused<<<dim3(2048 / BT), dim3(NTH), 0, stream>>>(
        x, Wih0, Whh0, bih0, bhh0, Wih1, Whh1, bih1, bhh1,
        Wih2, Whh2, bih2, bhh2, Wout, bout, (float*)d_out);
}

// Round 7
// 770.656 us; speedup vs baseline: 4.5713x; 1.0382x over previous
//
#include <hip/hip_runtime.h>

#define T_LEN 512
#define HID   40
#define BT    8        // sequences per block -> grid 256 = 1 block/CU
#define NTH   640      // 10 waves; wave w owns units u = 4w..4w+3 (all 4 gates)

typedef _Float16 f16x8 __attribute__((ext_vector_type(8)));
typedef float    f32x4 __attribute__((ext_vector_type(4)));

// B-fragment LDS: one buffer per layer, cols 0-7 = h_hi, cols 8-15 = h_lo.
// Chunked lane-linear layout (chunk = s*64+lane, 16B), parity double-buffered.
// Region offsets in fp16 units within one parity bank:
#define O_L0  0        // L0 (K-pad 64): 2 K-steps * 512 = 1024
#define O_L1  1024     // L1 (K-pad 96): 3 * 512 = 1536
#define O_L2  2560
#define PARSZ 4096     // fp16 per parity bank (8 KB); 2 banks = 16 KB

__device__ __forceinline__ float fast_rcp(float v) { return __builtin_amdgcn_rcpf(v); }
__device__ __forceinline__ float sigm(float v) { return fast_rcp(1.f + __expf(-v)); }
__device__ __forceinline__ float tanh_fast(float v) {
    return 2.f * fast_rcp(1.f + __expf(-2.f * v)) - 1.f;
}

__device__ __forceinline__ float dpp_add_xor1(float x) {
    return x + __int_as_float(__builtin_amdgcn_update_dpp(
                   0, __float_as_int(x), 0xB1, 0xF, 0xF, true));
}
__device__ __forceinline__ float dpp_add_xor2(float x) {
    return x + __int_as_float(__builtin_amdgcn_update_dpp(
                   0, __float_as_int(x), 0x4E, 0xF, 0xF, true));
}
// row_ror:8 — lane n receives lane (n+8)%16 of its 16-lane row. Pure VALU.
__device__ __forceinline__ float dpp_add_ror8(float x) {
    return x + __int_as_float(__builtin_amdgcn_update_dpp(
                   0, __float_as_int(x), 0x128, 0xF, 0xF, true));
}

// element index for (kpos, col): chunk = (k/32)*64 + ((k%32)/8)*16 + col, elem k%8
__device__ __forceinline__ int bidx(int kpos, int col) {
    return (((kpos >> 5) * 64) + (((kpos >> 3) & 3) * 16) + col) * 8 + (kpos & 7);
}
// write h split across the hi/lo column halves of one buffer
__device__ __forceinline__ void wr_split(_Float16* B, int kpos, int n, float v) {
    _Float16 hi = (_Float16)v;
    B[bidx(kpos, n)]     = hi;
    B[bidx(kpos, n + 8)] = (_Float16)(v - (float)hi);
}

// KS K-steps, ONE b128 read + two chained MFMA each: acc = Al*B + (Ah*B + acc).
template <int KS>
__device__ __forceinline__ f32x4 gemm2(const _Float16* __restrict__ B,
                                       const f16x8 (&Ah)[KS], const f16x8 (&Al)[KS],
                                       f32x4 acc, int lane) {
#pragma unroll
    for (int s = 0; s < KS; ++s) {
        f16x8 b = *(const f16x8*)(B + (s * 64 + lane) * 8);
        acc = __builtin_amdgcn_mfma_f32_16x16x32_f16(Ah[s], b, acc, 0, 0, 0);
        acc = __builtin_amdgcn_mfma_f32_16x16x32_f16(Al[s], b, acc, 0, 0, 0);
    }
    return acc;
}

__global__ __launch_bounds__(NTH, 2) void lstm_fused(
    const float* __restrict__ x,
    const float* __restrict__ Wih0, const float* __restrict__ Whh0,
    const float* __restrict__ bih0, const float* __restrict__ bhh0,
    const float* __restrict__ Wih1, const float* __restrict__ Whh1,
    const float* __restrict__ bih1, const float* __restrict__ bhh1,
    const float* __restrict__ Wih2, const float* __restrict__ Whh2,
    const float* __restrict__ bih2, const float* __restrict__ bhh2,
    const float* __restrict__ Wout, const float* __restrict__ bout,
    float* __restrict__ out) {
    __shared__ __attribute__((aligned(16))) _Float16 sBF[2 * PARSZ];   // 16 KB
    __shared__ __attribute__((aligned(16))) float    sY[4 * HID * BT]; // 5 KB

    const int tid  = threadIdx.x;
    const int lane = tid & 63;
    const int w    = tid >> 6;        // wave id = u-tile
    const int n    = lane & 15;       // B/D column (seq b when n<8; n>=8 = lo-half)
    const int quad = lane >> 4;
    const int u    = w * 4 + quad;    // hidden unit this lane owns (cell update)
    const int seq0 = blockIdx.x * BT;

    // ---- A-fragments: gate-permuted rows, split fp16, built once ----
    // tile row r -> gate j = (r%4)*40 + w*4 + r/4 ; lane supplies A row n, k=quad*8+jj
    const int ja = (n & 3) * 40 + w * 4 + (n >> 2);
    f16x8 A0h[2], A0l[2], A1h[3], A1l[3], A2h[3], A2l[3];
#pragma unroll
    for (int s = 0; s < 2; ++s)
#pragma unroll
        for (int jj = 0; jj < 8; ++jj) {
            int   k = s * 32 + quad * 8 + jj;
            float v = (k < 6) ? Wih0[ja * 6 + k] : (k < 46) ? Whh0[ja * 40 + (k - 6)] : 0.f;
            _Float16 hi = (_Float16)v;
            A0h[s][jj] = hi;
            A0l[s][jj] = (_Float16)(v - (float)hi);
        }
#pragma unroll
    for (int s = 0; s < 3; ++s)
#pragma unroll
        for (int jj = 0; jj < 8; ++jj) {
            int   k  = s * 32 + quad * 8 + jj;
            float v1 = (k < 40) ? Wih1[ja * 40 + k] : (k < 80) ? Whh1[ja * 40 + (k - 40)] : 0.f;
            float v2 = (k < 40) ? Wih2[ja * 40 + k] : (k < 80) ? Whh2[ja * 40 + (k - 40)] : 0.f;
            _Float16 h1 = (_Float16)v1, h2 = (_Float16)v2;
            A1h[s][jj] = h1; A1l[s][jj] = (_Float16)(v1 - (float)h1);
            A2h[s][jj] = h2; A2l[s][jj] = (_Float16)(v2 - (float)h2);
        }

    // biases: acc-init = bias*0.5 (exact) so hi-col + lo-col sum restores bias once
    f32x4 bia0, bia1, bia2;
#pragma unroll
    for (int reg = 0; reg < 4; ++reg) {
        int jr    = reg * 40 + u;
        bia0[reg] = 0.5f * (bih0[jr] + bhh0[jr]);
        bia1[reg] = 0.5f * (bih1[jr] + bhh1[jr]);
        bia2[reg] = 0.5f * (bih2[jr] + bhh2[jr]);
    }
    const float wov   = Wout[u];
    const float boutv = bout[0];

    float c0 = 0.f, c1 = 0.f, c2 = 0.f;  // cell states for (b=n, u), lanes n<8

    // ---- x prefetch lanes: 8 seq x 6 d ----
    const int    xb = tid / 6, xd = tid % 6;
    const float* xbase = x + (size_t)seq0 * T_LEN * 6;
    float        xr = 0.f;
    if (tid < 48) xr = xbase[xb * (T_LEN * 6) + 0 * 6 + xd];

    // zero both parity banks (K-pads stay zero forever)
    for (int i = tid; i < 2 * PARSZ / 8; i += NTH)
        *(float4*)&sBF[i * 8] = make_float4(0.f, 0.f, 0.f, 0.f);
    __syncthreads();
    if (tid < 48) {
        wr_split(sBF + O_L0, xd, xb, xr);            // x(0) -> parity 0
        xr = xbase[xb * (T_LEN * 6) + 1 * 6 + xd];   // prefetch x(1)
    }
    __syncthreads();

    for (int t = 0; t < T_LEN; ++t) {
        _Float16* P = sBF + (t & 1) * PARSZ;         // read parity
        _Float16* Q = sBF + ((t & 1) ^ 1) * PARSZ;   // write parity (next step)

        // ---- phase A: L0 gates + in-lane cell update ----
        {
            f32x4 acc = gemm2<2>(P + O_L0, A0h, A0l, bia0, lane);
            float ii = sigm(dpp_add_ror8(acc[0]));
            float ff = sigm(dpp_add_ror8(acc[1]));
            float gg = tanh_fast(dpp_add_ror8(acc[2]));
            float oo = sigm(dpp_add_ror8(acc[3]));
            c0       = ff * c0 + ii * gg;
            float h  = oo * tanh_fast(c0);
            if (n < 8) {
                wr_split(Q + O_L0, 6 + u, n, h);
                wr_split(P + O_L1, u, n, h);
            }
        }
        __syncthreads();
        // ---- phase B: L1 gates + update; x(t+1) staging ----
        {
            f32x4 acc = gemm2<3>(P + O_L1, A1h, A1l, bia1, lane);
            float ii = sigm(dpp_add_ror8(acc[0]));
            float ff = sigm(dpp_add_ror8(acc[1]));
            float gg = tanh_fast(dpp_add_ror8(acc[2]));
            float oo = sigm(dpp_add_ror8(acc[3]));
            c1       = ff * c1 + ii * gg;
            float h  = oo * tanh_fast(c1);
            if (n < 8) {
                wr_split(Q + O_L1, 40 + u, n, h);
                wr_split(P + O_L2, u, n, h);
            }
            if (tid < 48 && t + 1 < T_LEN) {
                wr_split(Q + O_L0, xd, xb, xr);
                if (t + 2 < T_LEN) xr = xbase[xb * (T_LEN * 6) + (t + 2) * 6 + xd];
            }
        }
        __syncthreads();
        // ---- phase C: L2 gates + update + y staging ----
        {
            f32x4 acc = gemm2<3>(P + O_L2, A2h, A2l, bia2, lane);
            float ii = sigm(dpp_add_ror8(acc[0]));
            float ff = sigm(dpp_add_ror8(acc[1]));
            float gg = tanh_fast(dpp_add_ror8(acc[2]));
            float oo = sigm(dpp_add_ror8(acc[3]));
            c2       = ff * c2 + ii * gg;
            float h  = oo * tanh_fast(c2);
            if (n < 8) {
                wr_split(Q + O_L2, 40 + u, n, h);
                sY[(t & 3) * (HID * BT) + u * BT + n] = h * wov;
            }
        }
        __syncthreads();
        // ---- every 4 steps: reduce sY -> 32 outputs (4 t x 8 seq) ----
        if ((t & 3) == 3 && tid < 128) {
            int o = tid >> 2, part = tid & 3;
            int tt = o >> 3, bb = o & 7;
            float s = 0.f;
#pragma unroll
            for (int i2 = 0; i2 < 10; ++i2)
                s += sY[tt * (HID * BT) + (part * 10 + i2) * BT + bb];
            s = dpp_add_xor1(s);
            s = dpp_add_xor2(s);
            if (part == 0)
                out[(size_t)(seq0 + bb) * T_LEN + (t - 3) + tt] = s + boutv;
        }
        // safe: sY slot rewritten 2 barriers after this read (phase C of t+1)
    }
}

extern "C" void kernel_launch(void* const* d_in, const int* in_sizes, int n_in,
                              void* d_out, int out_size, void* d_ws, size_t ws_size,
                              hipStream_t stream) {
    const float* x    = (const float*)d_in[0];
    const float* Wih0 = (const float*)d_in[1];
    const float* Whh0 = (const float*)d_in[2];
    const float* bih0 = (const float*)d_in[3];
    const float* bhh0 = (const float*)d_in[4];
    const float* Wih1 = (const float*)d_in[5];
    const float* Whh1 = (const float*)d_in[6];
    const float* bih1 = (const float*)d_in[7];
    const float* bhh1 = (const float*)d_in[8];
    const float* Wih2 = (const float*)d_in[9];
    const float* Whh2 = (const float*)d_in[10];
    const float* bih2 = (const float*)d_in[11];
    const float* bhh2 = (const float*)d_in[12];
    const float* Wout = (const float*)d_in[13];
    const float* bout = (const float*)d_in[14];

    lstm_fused<<<dim3(2048 / BT), dim3(NTH), 0, stream>>>(
        x, Wih0, Whh0, bih0, bhh0, Wih1, Whh1, bih1, bhh1,
        Wih2, Whh2, bih2, bhh2, Wout, bout, (float*)d_out);
}

// Round 8
// 736.845 us; speedup vs baseline: 4.7811x; 1.0459x over previous
//
#include <hip/hip_runtime.h>

#define T_LEN 512
#define HID   40
#define BT    8        // sequences per block -> grid 256 = 1 block/CU
#define NTH   640      // 10 waves; wave w owns units u = 4w..4w+3 (all 4 gates)

typedef _Float16 f16x8 __attribute__((ext_vector_type(8)));
typedef float    f32x4 __attribute__((ext_vector_type(4)));

// B-fragment LDS: one buffer per layer, cols 0-7 = h_hi, cols 8-15 = h_lo.
// Chunked lane-linear layout (chunk = s*64+lane, 16B), parity double-buffered.
#define O_L0  0        // L0 (K-pad 64): 2 K-steps * 512 = 1024
#define O_L1  1024     // L1 (K-pad 96): 3 * 512 = 1536
#define O_L2  2560
#define PARSZ 4096     // fp16 per parity bank (8 KB); 2 banks = 16 KB

__device__ __forceinline__ float fast_rcp(float v) { return __builtin_amdgcn_rcpf(v); }
__device__ __forceinline__ float sigm(float v) { return fast_rcp(1.f + __expf(-v)); }
__device__ __forceinline__ float tanh_fast(float v) {
    return 2.f * fast_rcp(1.f + __expf(-2.f * v)) - 1.f;
}

__device__ __forceinline__ float dpp_add_xor1(float x) {
    return x + __int_as_float(__builtin_amdgcn_update_dpp(
                   0, __float_as_int(x), 0xB1, 0xF, 0xF, true));
}
__device__ __forceinline__ float dpp_add_xor2(float x) {
    return x + __int_as_float(__builtin_amdgcn_update_dpp(
                   0, __float_as_int(x), 0x4E, 0xF, 0xF, true));
}
// row_ror:8 — lane n receives lane (n+8)%16 of its 16-lane row. Pure VALU.
__device__ __forceinline__ float dpp_add_ror8(float x) {
    return x + __int_as_float(__builtin_amdgcn_update_dpp(
                   0, __float_as_int(x), 0x128, 0xF, 0xF, true));
}

// element index for (kpos, col): chunk = (k/32)*64 + ((k%32)/8)*16 + col, elem k%8
__device__ __forceinline__ int bidx(int kpos, int col) {
    return (((kpos >> 5) * 64) + (((kpos >> 3) & 3) * 16) + col) * 8 + (kpos & 7);
}

// KS K-steps, ONE b128 read + two chained MFMA each: acc = Al*B + (Ah*B + acc).
template <int KS>
__device__ __forceinline__ f32x4 gemm2(const _Float16* __restrict__ B,
                                       const f16x8 (&Ah)[KS], const f16x8 (&Al)[KS],
                                       f32x4 acc, int lane) {
#pragma unroll
    for (int s = 0; s < KS; ++s) {
        f16x8 b = *(const f16x8*)(B + (s * 64 + lane) * 8);
        acc = __builtin_amdgcn_mfma_f32_16x16x32_f16(Ah[s], b, acc, 0, 0, 0);
        acc = __builtin_amdgcn_mfma_f32_16x16x32_f16(Al[s], b, acc, 0, 0, 0);
    }
    return acc;
}

__global__ __launch_bounds__(NTH, 1) void lstm_fused(
    const float* __restrict__ x,
    const float* __restrict__ Wih0, const float* __restrict__ Whh0,
    const float* __restrict__ bih0, const float* __restrict__ bhh0,
    const float* __restrict__ Wih1, const float* __restrict__ Whh1,
    const float* __restrict__ bih1, const float* __restrict__ bhh1,
    const float* __restrict__ Wih2, const float* __restrict__ Whh2,
    const float* __restrict__ bih2, const float* __restrict__ bhh2,
    const float* __restrict__ Wout, const float* __restrict__ bout,
    float* __restrict__ out) {
    __shared__ __attribute__((aligned(16))) _Float16 sBF[2 * PARSZ];   // 16 KB
    __shared__ __attribute__((aligned(16))) float    sY[4 * HID * BT]; // 5 KB

    const int tid  = threadIdx.x;
    const int lane = tid & 63;
    const int w    = tid >> 6;        // wave id = u-tile
    const int n    = lane & 15;       // B/D column (seq b when n<8; n>=8 = lo-half)
    const int quad = lane >> 4;
    const int u    = w * 4 + quad;    // hidden unit this lane owns (cell update)
    const int seq0 = blockIdx.x * BT;

    // ---- A-fragments: gate-permuted rows, split fp16, built once ----
    // tile row r -> gate j = (r%4)*40 + w*4 + r/4 ; lane supplies A row n, k=quad*8+jj
    const int ja = (n & 3) * 40 + w * 4 + (n >> 2);
    f16x8 A0h[2], A0l[2], A1h[3], A1l[3], A2h[3], A2l[3];
#pragma unroll
    for (int s = 0; s < 2; ++s)
#pragma unroll
        for (int jj = 0; jj < 8; ++jj) {
            int   k = s * 32 + quad * 8 + jj;
            float v = (k < 6) ? Wih0[ja * 6 + k] : (k < 46) ? Whh0[ja * 40 + (k - 6)] : 0.f;
            _Float16 hi = (_Float16)v;
            A0h[s][jj] = hi;
            A0l[s][jj] = (_Float16)(v - (float)hi);
        }
#pragma unroll
    for (int s = 0; s < 3; ++s)
#pragma unroll
        for (int jj = 0; jj < 8; ++jj) {
            int   k  = s * 32 + quad * 8 + jj;
            float v1 = (k < 40) ? Wih1[ja * 40 + k] : (k < 80) ? Whh1[ja * 40 + (k - 40)] : 0.f;
            float v2 = (k < 40) ? Wih2[ja * 40 + k] : (k < 80) ? Whh2[ja * 40 + (k - 40)] : 0.f;
            _Float16 h1 = (_Float16)v1, h2 = (_Float16)v2;
            A1h[s][jj] = h1; A1l[s][jj] = (_Float16)(v1 - (float)h1);
            A2h[s][jj] = h2; A2l[s][jj] = (_Float16)(v2 - (float)h2);
        }

    // biases: acc-init = bias*0.5 (exact) so hi-col + lo-col sum restores bias once
    f32x4 bia0, bia1, bia2;
#pragma unroll
    for (int reg = 0; reg < 4; ++reg) {
        int jr    = reg * 40 + u;
        bia0[reg] = 0.5f * (bih0[jr] + bhh0[jr]);
        bia1[reg] = 0.5f * (bih1[jr] + bhh1[jr]);
        bia2[reg] = 0.5f * (bih2[jr] + bhh2[jr]);
    }
    const float wov   = Wout[u];
    const float boutv = bout[0];

    float c0 = 0.f, c1 = 0.f, c2 = 0.f;  // cell states for (b=n, u), lanes n<8

    // ---- loop-invariant LDS write indices (force hoisting) ----
    const int iU_h  = bidx(6 + u, n),  iU_l  = bidx(6 + u, n + 8);   // L0 h-slot
    const int iIN_h = bidx(u, n),      iIN_l = bidx(u, n + 8);       // L1/L2 input slot
    const int iH_h  = bidx(40 + u, n), iH_l  = bidx(40 + u, n + 8);  // L1/L2 h-slot

    // ---- x prefetch lanes: 8 seq x 6 d ----
    const int    xb = tid / 6, xd = tid % 6;
    const int    ix_h = bidx(xd, xb), ix_l = bidx(xd, xb + 8);
    const float* xbase = x + (size_t)seq0 * T_LEN * 6;
    float        xr = 0.f;
    if (tid < 48) xr = xbase[xb * (T_LEN * 6) + 0 * 6 + xd];

    // zero both parity banks (K-pads stay zero forever)
    for (int i = tid; i < 2 * PARSZ / 8; i += NTH)
        *(float4*)&sBF[i * 8] = make_float4(0.f, 0.f, 0.f, 0.f);
    __syncthreads();
    if (tid < 48) {
        _Float16 hi = (_Float16)xr;
        sBF[O_L0 + ix_h] = hi;                        // x(0) -> parity 0
        sBF[O_L0 + ix_l] = (_Float16)(xr - (float)hi);
        xr = xbase[xb * (T_LEN * 6) + 1 * 6 + xd];    // prefetch x(1)
    }
    __syncthreads();

    auto step = [&](_Float16* __restrict__ P, _Float16* __restrict__ Q, int t) {
        // ---- phase A: L0 gates + in-lane cell update ----
        {
            f32x4 acc = gemm2<2>(P + O_L0, A0h, A0l, bia0, lane);
            float ii = sigm(dpp_add_ror8(acc[0]));
            float ff = sigm(dpp_add_ror8(acc[1]));
            float gg = tanh_fast(dpp_add_ror8(acc[2]));
            float oo = sigm(dpp_add_ror8(acc[3]));
            c0       = ff * c0 + ii * gg;
            float h  = oo * tanh_fast(c0);
            if (n < 8) {
                _Float16 hi = (_Float16)h;
                _Float16 lo = (_Float16)(h - (float)hi);
                Q[O_L0 + iU_h]  = hi;  Q[O_L0 + iU_l]  = lo;
                P[O_L1 + iIN_h] = hi;  P[O_L1 + iIN_l] = lo;
            }
        }
        __syncthreads();
        // ---- phase B: L1 gates + update; x(t+1) staging ----
        {
            f32x4 acc = gemm2<3>(P + O_L1, A1h, A1l, bia1, lane);
            float ii = sigm(dpp_add_ror8(acc[0]));
            float ff = sigm(dpp_add_ror8(acc[1]));
            float gg = tanh_fast(dpp_add_ror8(acc[2]));
            float oo = sigm(dpp_add_ror8(acc[3]));
            c1       = ff * c1 + ii * gg;
            float h  = oo * tanh_fast(c1);
            if (n < 8) {
                _Float16 hi = (_Float16)h;
                _Float16 lo = (_Float16)(h - (float)hi);
                Q[O_L1 + iH_h]  = hi;  Q[O_L1 + iH_l]  = lo;
                P[O_L2 + iIN_h] = hi;  P[O_L2 + iIN_l] = lo;
            }
            if (tid < 48 && t + 1 < T_LEN) {
                _Float16 hi = (_Float16)xr;
                Q[O_L0 + ix_h] = hi;
                Q[O_L0 + ix_l] = (_Float16)(xr - (float)hi);
                if (t + 2 < T_LEN) xr = xbase[xb * (T_LEN * 6) + (t + 2) * 6 + xd];
            }
        }
        __syncthreads();
        // ---- phase C: L2 gates + update + y staging ----
        {
            f32x4 acc = gemm2<3>(P + O_L2, A2h, A2l, bia2, lane);
            float ii = sigm(dpp_add_ror8(acc[0]));
            float ff = sigm(dpp_add_ror8(acc[1]));
            float gg = tanh_fast(dpp_add_ror8(acc[2]));
            float oo = sigm(dpp_add_ror8(acc[3]));
            c2       = ff * c2 + ii * gg;
            float h  = oo * tanh_fast(c2);
            if (n < 8) {
                _Float16 hi = (_Float16)h;
                _Float16 lo = (_Float16)(h - (float)hi);
                Q[O_L2 + iH_h] = hi;  Q[O_L2 + iH_l] = lo;
                sY[(t & 3) * (HID * BT) + u * BT + n] = h * wov;
            }
        }
        __syncthreads();
        // ---- every 4 steps: reduce sY -> 32 outputs (4 t x 8 seq) ----
        if ((t & 3) == 3 && tid < 128) {
            int o = tid >> 2, part = tid & 3;
            int tt = o >> 3, bb = o & 7;
            float s = 0.f;
#pragma unroll
            for (int i2 = 0; i2 < 10; ++i2)
                s += sY[tt * (HID * BT) + (part * 10 + i2) * BT + bb];
            s = dpp_add_xor1(s);
            s = dpp_add_xor2(s);
            if (part == 0)
                out[(size_t)(seq0 + bb) * T_LEN + (t - 3) + tt] = s + boutv;
        }
        // safe: sY slot rewritten 2 barriers after this read (phase C of t+1)
    };

    for (int t = 0; t < T_LEN; t += 2) {
        step(sBF,         sBF + PARSZ, t);      // even: read parity 0, write parity 1
        step(sBF + PARSZ, sBF,         t + 1);  // odd:  read parity 1, write parity 0
    }
}

extern "C" void kernel_launch(void* const* d_in, const int* in_sizes, int n_in,
                              void* d_out, int out_size, void* d_ws, size_t ws_size,
                              hipStream_t stream) {
    const float* x    = (const float*)d_in[0];
    const float* Wih0 = (const float*)d_in[1];
    const float* Whh0 = (const float*)d_in[2];
    const float* bih0 = (const float*)d_in[3];
    const float* bhh0 = (const float*)d_in[4];
    const float* Wih1 = (const float*)d_in[5];
    const float* Whh1 = (const float*)d_in[6];
    const float* bih1 = (const float*)d_in[7];
    const float* bhh1 = (const float*)d_in[8];
    const float* Wih2 = (const float*)d_in[9];
    const float* Whh2 = (const float*)d_in[10];
    const float* bih2 = (const float*)d_in[11];
    const float* bhh2 = (const float*)d_in[12];
    const float* Wout = (const float*)d_in[13];
    const float* bout = (const float*)d_in[14];

    lstm_fused<<<dim3(2048 / BT), dim3(NTH), 0, stream>>>(
        x, Wih0, Whh0, bih0, bhh0, Wih1, Whh1, bih1, bhh1,
        Wih2, Whh2, bih2, bhh2, Wout, bout, (float*)d_out);
}

// Round 9
// 662.959 us; speedup vs baseline: 5.3139x; 1.1114x over previous
//
#include <hip/hip_runtime.h>

#define T_LEN 512
#define HID   40
#define BT    8        // sequences per block -> grid 256 = 1 block/CU
#define NTH   640      // 10 waves; wave w owns units u = 4w..4w+3 (all 4 gates)

typedef _Float16 f16x8 __attribute__((ext_vector_type(8)));
typedef float    f32x4 __attribute__((ext_vector_type(4)));

// B-fragment LDS: one buffer per layer, cols 0-7 = h_hi, cols 8-15 = h_lo.
// Chunked lane-linear layout (chunk = s*64+lane, 16B), parity double-buffered.
#define O_L0  0        // L0 (K-pad 64): 2 K-steps * 512 = 1024
#define O_L1  1024     // L1 (K-pad 96): 3 * 512 = 1536
#define O_L2  2560
#define PARSZ 4096     // fp16 per parity bank (8 KB); 2 banks = 16 KB

__device__ __forceinline__ float fast_rcp(float v) { return __builtin_amdgcn_rcpf(v); }
__device__ __forceinline__ float sigm(float v) { return fast_rcp(1.f + __expf(-v)); }
__device__ __forceinline__ float tanh_fast(float v) {
    return 2.f * fast_rcp(1.f + __expf(-2.f * v)) - 1.f;
}

__device__ __forceinline__ float dpp_add_xor1(float x) {
    return x + __int_as_float(__builtin_amdgcn_update_dpp(
                   0, __float_as_int(x), 0xB1, 0xF, 0xF, true));
}
__device__ __forceinline__ float dpp_add_xor2(float x) {
    return x + __int_as_float(__builtin_amdgcn_update_dpp(
                   0, __float_as_int(x), 0x4E, 0xF, 0xF, true));
}
// row_ror:8 — lane n receives lane (n+8)%16 of its 16-lane row. Pure VALU.
__device__ __forceinline__ float dpp_add_ror8(float x) {
    return x + __int_as_float(__builtin_amdgcn_update_dpp(
                   0, __float_as_int(x), 0x128, 0xF, 0xF, true));
}

// element index for (kpos, col): chunk = (k/32)*64 + ((k%32)/8)*16 + col, elem k%8
__device__ __forceinline__ int bidx(int kpos, int col) {
    return (((kpos >> 5) * 64) + (((kpos >> 3) & 3) * 16) + col) * 8 + (kpos & 7);
}

// KS K-steps, ONE b128 read + two chained MFMA each: acc = Al*B + (Ah*B + acc).
template <int KS>
__device__ __forceinline__ f32x4 gemm2(const _Float16* __restrict__ B,
                                       const f16x8 (&Ah)[KS], const f16x8 (&Al)[KS],
                                       f32x4 acc, int lane) {
#pragma unroll
    for (int s = 0; s < KS; ++s) {
        f16x8 b = *(const f16x8*)(B + (s * 64 + lane) * 8);
        acc = __builtin_amdgcn_mfma_f32_16x16x32_f16(Ah[s], b, acc, 0, 0, 0);
        acc = __builtin_amdgcn_mfma_f32_16x16x32_f16(Al[s], b, acc, 0, 0, 0);
    }
    return acc;
}

__global__ __launch_bounds__(NTH, 1) void lstm_fused(
    const float* __restrict__ x,
    const float* __restrict__ Wih0, const float* __restrict__ Whh0,
    const float* __restrict__ bih0, const float* __restrict__ bhh0,
    const float* __restrict__ Wih1, const float* __restrict__ Whh1,
    const float* __restrict__ bih1, const float* __restrict__ bhh1,
    const float* __restrict__ Wih2, const float* __restrict__ Whh2,
    const float* __restrict__ bih2, const float* __restrict__ bhh2,
    const float* __restrict__ Wout, const float* __restrict__ bout,
    float* __restrict__ out) {
    __shared__ __attribute__((aligned(16))) _Float16 sBF[2 * PARSZ];   // 16 KB
    __shared__ __attribute__((aligned(16))) float    sY[8 * HID * BT]; // 10 KB, 8 slots

    const int tid  = threadIdx.x;
    const int lane = tid & 63;
    const int w    = tid >> 6;        // wave id = u-tile
    const int n    = lane & 15;       // B/D column (seq b when n<8; n>=8 = lo-half)
    const int quad = lane >> 4;
    const int u    = w * 4 + quad;    // hidden unit this lane owns (cell update)
    const int seq0 = blockIdx.x * BT;

    // ---- A-fragments: gate-permuted rows, split fp16, built once ----
    // tile row r -> gate j = (r%4)*40 + w*4 + r/4 ; lane supplies A row n, k=quad*8+jj
    const int ja = (n & 3) * 40 + w * 4 + (n >> 2);
    f16x8 A0h[2], A0l[2], A1h[3], A1l[3], A2h[3], A2l[3];
#pragma unroll
    for (int s = 0; s < 2; ++s)
#pragma unroll
        for (int jj = 0; jj < 8; ++jj) {
            int   k = s * 32 + quad * 8 + jj;
            float v = (k < 6) ? Wih0[ja * 6 + k] : (k < 46) ? Whh0[ja * 40 + (k - 6)] : 0.f;
            _Float16 hi = (_Float16)v;
            A0h[s][jj] = hi;
            A0l[s][jj] = (_Float16)(v - (float)hi);
        }
#pragma unroll
    for (int s = 0; s < 3; ++s)
#pragma unroll
        for (int jj = 0; jj < 8; ++jj) {
            int   k  = s * 32 + quad * 8 + jj;
            float v1 = (k < 40) ? Wih1[ja * 40 + k] : (k < 80) ? Whh1[ja * 40 + (k - 40)] : 0.f;
            float v2 = (k < 40) ? Wih2[ja * 40 + k] : (k < 80) ? Whh2[ja * 40 + (k - 40)] : 0.f;
            _Float16 h1 = (_Float16)v1, h2 = (_Float16)v2;
            A1h[s][jj] = h1; A1l[s][jj] = (_Float16)(v1 - (float)h1);
            A2h[s][jj] = h2; A2l[s][jj] = (_Float16)(v2 - (float)h2);
        }

    // biases: acc-init = bias*0.5 (exact) so hi-col + lo-col sum restores bias once
    f32x4 bia0, bia1, bia2;
#pragma unroll
    for (int reg = 0; reg < 4; ++reg) {
        int jr    = reg * 40 + u;
        bia0[reg] = 0.5f * (bih0[jr] + bhh0[jr]);
        bia1[reg] = 0.5f * (bih1[jr] + bhh1[jr]);
        bia2[reg] = 0.5f * (bih2[jr] + bhh2[jr]);
    }
    const float wov   = Wout[u];
    const float boutv = bout[0];

    float c0 = 0.f, c1 = 0.f, c2 = 0.f;  // cell states for (b=n, u), lanes n<8

    // ---- loop-invariant LDS write indices ----
    const int iU_h  = bidx(6 + u, n),  iU_l  = bidx(6 + u, n + 8);   // L0 h-slot
    const int iIN_h = bidx(u, n),      iIN_l = bidx(u, n + 8);       // L1/L2 input slot
    const int iH_h  = bidx(40 + u, n), iH_l  = bidx(40 + u, n + 8);  // L1/L2 h-slot

    // ---- x prefetch lanes: 8 seq x 6 d ----
    const int    xb = tid / 6, xd = tid % 6;
    const int    ix_h = bidx(xd, xb), ix_l = bidx(xd, xb + 8);
    const float* xbase = x + (size_t)seq0 * T_LEN * 6;
    float        xr = 0.f;
    if (tid < 48) xr = xbase[xb * (T_LEN * 6) + 0 * 6 + xd];

    // zero both parity banks (K-pads stay zero forever)
    for (int i = tid; i < 2 * PARSZ / 8; i += NTH)
        *(float4*)&sBF[i * 8] = make_float4(0.f, 0.f, 0.f, 0.f);
    __syncthreads();
    if (tid < 48) {
        _Float16 hi = (_Float16)xr;
        sBF[O_L0 + ix_h] = hi;                        // x(0) -> parity 0
        sBF[O_L0 + ix_l] = (_Float16)(xr - (float)hi);
        xr = xbase[xb * (T_LEN * 6) + 1 * 6 + xd];    // prefetch x(1)
    }
    __syncthreads();

    // lagged output flush: group of 4 timesteps ending at t2g+3
    auto flushY = [&](int t2g) {
        int o = tid >> 2, part = tid & 3;
        int tt = o >> 3, bb = o & 7;
        int slot = (t2g + tt) & 7;
        float s = 0.f;
#pragma unroll
        for (int i2 = 0; i2 < 10; ++i2)
            s += sY[slot * (HID * BT) + (part * 10 + i2) * BT + bb];
        s = dpp_add_xor1(s);
        s = dpp_add_xor2(s);
        if (part == 0)
            out[(size_t)(seq0 + bb) * T_LEN + t2g + tt] = s + boutv;
    };

    // One pipeline interval k: L0(t=k), L1(t=k-1), L2(t=k-2). Reads P, writes Q,
    // ONE barrier. The three gemm/activation chains are independent -> 3x ILP.
    auto interval = [&](_Float16* __restrict__ P, _Float16* __restrict__ Q,
                        int k, bool a0, bool a1, bool a2) {
        f32x4 acc0, acc1, acc2;
        if (a0) acc0 = gemm2<2>(P + O_L0, A0h, A0l, bia0, lane);
        if (a1) acc1 = gemm2<3>(P + O_L1, A1h, A1l, bia1, lane);
        if (a2) acc2 = gemm2<3>(P + O_L2, A2h, A2l, bia2, lane);

        if (a0) {
            float ii = sigm(dpp_add_ror8(acc0[0]));
            float ff = sigm(dpp_add_ror8(acc0[1]));
            float gg = tanh_fast(dpp_add_ror8(acc0[2]));
            float oo = sigm(dpp_add_ror8(acc0[3]));
            c0       = ff * c0 + ii * gg;
            float h  = oo * tanh_fast(c0);
            if (n < 8) {
                _Float16 hi = (_Float16)h, lo = (_Float16)(h - (float)hi);
                Q[O_L0 + iU_h]  = hi;  Q[O_L0 + iU_l]  = lo;
                Q[O_L1 + iIN_h] = hi;  Q[O_L1 + iIN_l] = lo;
            }
            if (tid < 48 && k + 1 < T_LEN) {   // stage x(k+1) for next interval
                _Float16 hi = (_Float16)xr;
                Q[O_L0 + ix_h] = hi;
                Q[O_L0 + ix_l] = (_Float16)(xr - (float)hi);
                if (k + 2 < T_LEN) xr = xbase[xb * (T_LEN * 6) + (k + 2) * 6 + xd];
            }
        }
        if (a1) {
            float ii = sigm(dpp_add_ror8(acc1[0]));
            float ff = sigm(dpp_add_ror8(acc1[1]));
            float gg = tanh_fast(dpp_add_ror8(acc1[2]));
            float oo = sigm(dpp_add_ror8(acc1[3]));
            c1       = ff * c1 + ii * gg;
            float h  = oo * tanh_fast(c1);
            if (n < 8) {
                _Float16 hi = (_Float16)h, lo = (_Float16)(h - (float)hi);
                Q[O_L1 + iH_h]  = hi;  Q[O_L1 + iH_l]  = lo;
                Q[O_L2 + iIN_h] = hi;  Q[O_L2 + iIN_l] = lo;
            }
        }
        if (a2) {
            float ii = sigm(dpp_add_ror8(acc2[0]));
            float ff = sigm(dpp_add_ror8(acc2[1]));
            float gg = tanh_fast(dpp_add_ror8(acc2[2]));
            float oo = sigm(dpp_add_ror8(acc2[3]));
            c2       = ff * c2 + ii * gg;
            float h  = oo * tanh_fast(c2);
            if (n < 8) {
                _Float16 hi = (_Float16)h, lo = (_Float16)(h - (float)hi);
                Q[O_L2 + iH_h] = hi;  Q[O_L2 + iH_l] = lo;
                sY[((k - 2) & 7) * (HID * BT) + u * BT + n] = h * wov;
            }
        }
        // flush group (k-8..k-5): slots disjoint from this interval's write slot
        if ((k & 3) == 0 && k >= 8 && tid < 128) flushY(k - 8);
        __syncthreads();
    };

    // pipeline fill
    interval(sBF,         sBF + PARSZ, 0, true, false, false);
    interval(sBF + PARSZ, sBF,         1, true, true,  false);
    // steady state: k = 2..511, parity-unrolled x2
    for (int k = 2; k < T_LEN; k += 2) {
        interval(sBF,         sBF + PARSZ, k,     true, true, true);
        interval(sBF + PARSZ, sBF,         k + 1, true, true, true);
    }
    // pipeline drain (k=512 even -> reads parity 0)
    interval(sBF,         sBF + PARSZ, T_LEN,     false, true,  true);
    interval(sBF + PARSZ, sBF,         T_LEN + 1, false, false, true);
    // tail flush: t2 = 508..511 (barrier at end of last interval orders sY)
    if (tid < 128) flushY(T_LEN - 4);
}

extern "C" void kernel_launch(void* const* d_in, const int* in_sizes, int n_in,
                              void* d_out, int out_size, void* d_ws, size_t ws_size,
                              hipStream_t stream) {
    const float* x    = (const float*)d_in[0];
    const float* Wih0 = (const float*)d_in[1];
    const float* Whh0 = (const float*)d_in[2];
    const float* bih0 = (const float*)d_in[3];
    const float* bhh0 = (const float*)d_in[4];
    const float* Wih1 = (const float*)d_in[5];
    const float* Whh1 = (const float*)d_in[6];
    const float* bih1 = (const float*)d_in[7];
    const float* bhh1 = (const float*)d_in[8];
    const float* Wih2 = (const float*)d_in[9];
    const float* Whh2 = (const float*)d_in[10];
    const float* bih2 = (const float*)d_in[11];
    const float* bhh2 = (const float*)d_in[12];
    const float* Wout = (const float*)d_in[13];
    const float* bout = (const float*)d_in[14];

    lstm_fused<<<dim3(2048 / BT), dim3(NTH), 0, stream>>>(
        x, Wih0, Whh0, bih0, bhh0, Wih1, Whh1, bih1, bhh1,
        Wih2, Whh2, bih2, bhh2, Wout, bout, (float*)d_out);
}

// Round 10
// 565.785 us; speedup vs baseline: 6.2266x; 1.1717x over previous
//
#include <hip/hip_runtime.h>

#define T_LEN 512
#define HID   40
#define BT    8        // sequences per block -> grid 256 = 1 block/CU
#define NTH   640      // 10 waves; wave w owns units u = 4w..4w+3 (all 4 gates)

typedef _Float16 f16x8 __attribute__((ext_vector_type(8)));
typedef float    f32x4 __attribute__((ext_vector_type(4)));

// B-fragment LDS: one buffer per layer, cols 0-7 = h_hi, cols 8-15 = h_lo.
// Chunked lane-linear layout (chunk = s*64+lane, 16B), parity double-buffered.
#define O_L0  0        // L0 (K-pad 64): 2 K-steps * 512 = 1024
#define O_L1  1024     // L1 (K-pad 96): 3 * 512 = 1536
#define O_L2  2560
#define PARSZ 4096     // fp16 per parity bank (8 KB); 2 banks = 16 KB

#define NLOG2E  (-1.4426950408889634f)   // -log2(e): sigmoid-gate pre-scale
#define N2LOG2E (-2.8853900817779268f)   // -2*log2(e): tanh-gate pre-scale

__device__ __forceinline__ float fast_rcp(float v)  { return __builtin_amdgcn_rcpf(v); }
__device__ __forceinline__ float fast_exp2(float v) { return __builtin_amdgcn_exp2f(v); }

__device__ __forceinline__ float dpp_add_xor1(float x) {
    return x + __int_as_float(__builtin_amdgcn_update_dpp(
                   0, __float_as_int(x), 0xB1, 0xF, 0xF, true));
}
__device__ __forceinline__ float dpp_add_xor2(float x) {
    return x + __int_as_float(__builtin_amdgcn_update_dpp(
                   0, __float_as_int(x), 0x4E, 0xF, 0xF, true));
}
// row_ror:8 — lane n receives lane (n+8)%16 of its 16-lane row. Pure VALU.
__device__ __forceinline__ float dpp_add_ror8(float x) {
    return x + __int_as_float(__builtin_amdgcn_update_dpp(
                   0, __float_as_int(x), 0x128, 0xF, 0xF, true));
}
__device__ __forceinline__ float dpp_mov_ror8(float x) {
    return __int_as_float(__builtin_amdgcn_update_dpp(
               0, __float_as_int(x), 0x128, 0xF, 0xF, true));
}

// element index for (kpos, col): chunk = (k/32)*64 + ((k%32)/8)*16 + col, elem k%8
__device__ __forceinline__ int bidx(int kpos, int col) {
    return (((kpos >> 5) * 64) + (((kpos >> 3) & 3) * 16) + col) * 8 + (kpos & 7);
}

// KS K-steps, ONE b128 read + two chained MFMA each: acc = Al*B + (Ah*B + acc).
template <int KS>
__device__ __forceinline__ f32x4 gemm2(const _Float16* __restrict__ B,
                                       const f16x8 (&Ah)[KS], const f16x8 (&Al)[KS],
                                       f32x4 acc, int lane) {
#pragma unroll
    for (int s = 0; s < KS; ++s) {
        f16x8 b = *(const f16x8*)(B + (s * 64 + lane) * 8);
        acc = __builtin_amdgcn_mfma_f32_16x16x32_f16(Ah[s], b, acc, 0, 0, 0);
        acc = __builtin_amdgcn_mfma_f32_16x16x32_f16(Al[s], b, acc, 0, 0, 0);
    }
    return acc;
}

__global__ __launch_bounds__(NTH, 1) void lstm_fused(
    const float* __restrict__ x,
    const float* __restrict__ Wih0, const float* __restrict__ Whh0,
    const float* __restrict__ bih0, const float* __restrict__ bhh0,
    const float* __restrict__ Wih1, const float* __restrict__ Whh1,
    const float* __restrict__ bih1, const float* __restrict__ bhh1,
    const float* __restrict__ Wih2, const float* __restrict__ Whh2,
    const float* __restrict__ bih2, const float* __restrict__ bhh2,
    const float* __restrict__ Wout, const float* __restrict__ bout,
    float* __restrict__ out) {
    __shared__ __attribute__((aligned(16))) _Float16 sBF[2 * PARSZ];   // 16 KB
    __shared__ __attribute__((aligned(16))) float    sY[8 * HID * BT]; // 10 KB, 8 slots

    const int  tid  = threadIdx.x;
    const int  lane = tid & 63;
    const int  w    = tid >> 6;       // wave id = u-tile
    const int  n    = lane & 15;      // B/D column (seq b when n<8; n>=8 = lo-half)
    const int  quad = lane >> 4;
    const int  u    = w * 4 + quad;   // hidden unit this lane owns (cell update)
    const int  seq0 = blockIdx.x * BT;
    const bool hiL  = (n < 8);        // hi-half lane?

    // ---- A-fragments: gate-permuted rows, split fp16, PRE-SCALED so all
    // activations become rcp(1+exp2(acc)): sigmoid rows x(-log2e), tanh rows
    // x(-2log2e). tile row r -> gate j = (r%4)*40 + w*4 + r/4.
    const int   ja  = (n & 3) * 40 + w * 4 + (n >> 2);
    const float sca = ((n & 3) == 2) ? N2LOG2E : NLOG2E;
    f16x8 A0h[2], A0l[2], A1h[3], A1l[3], A2h[3], A2l[3];
#pragma unroll
    for (int s = 0; s < 2; ++s)
#pragma unroll
        for (int jj = 0; jj < 8; ++jj) {
            int   k = s * 32 + quad * 8 + jj;
            float v = (k < 6) ? Wih0[ja * 6 + k] : (k < 46) ? Whh0[ja * 40 + (k - 6)] : 0.f;
            v *= sca;
            _Float16 hi = (_Float16)v;
            A0h[s][jj] = hi;
            A0l[s][jj] = (_Float16)(v - (float)hi);
        }
#pragma unroll
    for (int s = 0; s < 3; ++s)
#pragma unroll
        for (int jj = 0; jj < 8; ++jj) {
            int   k  = s * 32 + quad * 8 + jj;
            float v1 = (k < 40) ? Wih1[ja * 40 + k] : (k < 80) ? Whh1[ja * 40 + (k - 40)] : 0.f;
            float v2 = (k < 40) ? Wih2[ja * 40 + k] : (k < 80) ? Whh2[ja * 40 + (k - 40)] : 0.f;
            v1 *= sca; v2 *= sca;
            _Float16 h1 = (_Float16)v1, h2 = (_Float16)v2;
            A1h[s][jj] = h1; A1l[s][jj] = (_Float16)(v1 - (float)h1);
            A2h[s][jj] = h2; A2l[s][jj] = (_Float16)(v2 - (float)h2);
        }

    // biases: acc-init = 0.5*scale*bias (0.5 exact; hi+lo col fold restores 1x)
    f32x4 bia0, bia1, bia2;
#pragma unroll
    for (int reg = 0; reg < 4; ++reg) {
        int   jr = reg * 40 + u;
        float sc = 0.5f * ((reg == 2) ? N2LOG2E : NLOG2E);
        bia0[reg] = sc * (bih0[jr] + bhh0[jr]);
        bia1[reg] = sc * (bih1[jr] + bhh1[jr]);
        bia2[reg] = sc * (bih2[jr] + bhh2[jr]);
    }
    const float wov   = Wout[u];
    const float boutv = bout[0];

    float c0 = 0.f, c1 = 0.f, c2 = 0.f;  // cell states (duplicated on lane pair)

    // ---- loop-invariant LDS write indices: lane's own column (hi or lo) ----
    const int iU  = bidx(6 + u, n);   // L0 h-slot
    const int iIN = bidx(u, n);       // L1/L2 input slot
    const int iH  = bidx(40 + u, n);  // L1/L2 h-slot

    // ---- x staging on waves 2,3 (SIMDs 2,3 = the 2-compute-wave SIMDs) ----
    // 96 lanes: e = tid-128 -> seq s_idx = e/12, r = e%12, d = r%6, half = r/6
    const bool   xact = (tid >= 128 && tid < 224);
    const int    e    = tid - 128;
    const int    xs   = e / 12, xrr = e % 12;
    const int    xd   = xrr % 6, xhalf = xrr / 6;
    const int    ixi  = bidx(xd, xs + xhalf * 8);
    const float* xbl  = x + ((size_t)(seq0 + xs) * T_LEN) * 6 + xd;
    float        xr   = 0.f;
    if (xact) xr = xbl[0];  // x(0)

    // zero both parity banks (K-pads stay zero forever)
    for (int i = tid; i < 2 * PARSZ / 8; i += NTH)
        *(float4*)&sBF[i * 8] = make_float4(0.f, 0.f, 0.f, 0.f);
    __syncthreads();
    if (xact) {
        _Float16 hi = (_Float16)xr;
        sBF[O_L0 + ixi] = xhalf ? (_Float16)(xr - (float)hi) : hi;  // x(0) -> parity 0
        xr = xbl[6];                                                 // prefetch x(1)
    }
    __syncthreads();

    // activation: fold hi/lo cols, split trans across the lane pair, exchange,
    // duplicate cell update on both lanes. Returns h.
    auto activate = [&](f32x4 acc, float& c) -> float {
        float g0 = dpp_add_ror8(acc[0]);   // i (sigmoid-domain)
        float g1 = dpp_add_ror8(acc[1]);   // f
        float g2 = dpp_add_ror8(acc[2]);   // g (tanh-domain, pre-scaled 2x)
        float g3 = dpp_add_ror8(acc[3]);   // o
        float in0 = hiL ? g0 : g2;
        float in1 = hiL ? g1 : g3;
        float s0  = fast_rcp(1.f + fast_exp2(in0));
        float v0  = hiL ? s0 : (2.f * s0 - 1.f);   // hi: sig(i)  lo: tanh(g)
        float v1  = fast_rcp(1.f + fast_exp2(in1)); // hi: sig(f)  lo: sig(o)
        float r0  = dpp_mov_ror8(v0);
        float r1  = dpp_mov_ror8(v1);
        float ig  = v0 * r0;                        // sig(i)*tanh(g) on both
        float fs  = hiL ? v1 : r1;
        float os  = hiL ? r1 : v1;
        c = fs * c + ig;
        float th = 2.f * fast_rcp(1.f + fast_exp2(c * N2LOG2E)) - 1.f;
        return os * th;
    };
    auto packval = [&](float h) -> _Float16 {
        _Float16 hi = (_Float16)h;
        _Float16 lo = (_Float16)(h - (float)hi);
        return hiL ? hi : lo;
    };

    // lagged output flush on waves 2,3: group of 4 timesteps ending at t2g+3
    auto flushY = [&](int t2g) {
        int q = tid - 128, o = q >> 2, part = q & 3;
        int tt = o >> 3, bb = o & 7;
        int slot = (t2g + tt) & 7;
        float s = 0.f;
#pragma unroll
        for (int i2 = 0; i2 < 10; ++i2)
            s += sY[slot * (HID * BT) + (part * 10 + i2) * BT + bb];
        s = dpp_add_xor1(s);
        s = dpp_add_xor2(s);
        if (part == 0)
            out[(size_t)(seq0 + bb) * T_LEN + t2g + tt] = s + boutv;
    };

    // One pipeline interval k: L0(t=k), L1(t=k-1), L2(t=k-2). Reads P, writes Q,
    // ONE barrier. The three gemm/activation chains are independent -> 3x ILP.
    auto interval = [&](_Float16* __restrict__ P, _Float16* __restrict__ Q,
                        int k, bool a0, bool a1, bool a2) {
        f32x4 acc0, acc1, acc2;
        if (a0) acc0 = gemm2<2>(P + O_L0, A0h, A0l, bia0, lane);
        if (a1) acc1 = gemm2<3>(P + O_L1, A1h, A1l, bia1, lane);
        if (a2) acc2 = gemm2<3>(P + O_L2, A2h, A2l, bia2, lane);

        if (a0) {
            float h = activate(acc0, c0);
            _Float16 v = packval(h);
            Q[O_L0 + iU]  = v;   // full-wave: hi-lanes write hi, lo-lanes lo
            Q[O_L1 + iIN] = v;
        }
        if (a1) {
            float h = activate(acc1, c1);
            _Float16 v = packval(h);
            Q[O_L1 + iH]  = v;
            Q[O_L2 + iIN] = v;
        }
        if (a2) {
            float h = activate(acc2, c2);
            _Float16 v = packval(h);
            Q[O_L2 + iH] = v;
            if (hiL) sY[((k - 2) & 7) * (HID * BT) + u * BT + n] = h * wov;
        }
        if (xact && k + 1 < T_LEN) {   // stage x(k+1) for next interval
            _Float16 hi = (_Float16)xr;
            Q[O_L0 + ixi] = xhalf ? (_Float16)(xr - (float)hi) : hi;
            if (k + 2 < T_LEN) xr = xbl[(size_t)(k + 2) * 6];
        }
        // flush group (k-8..k-5): slots disjoint from this interval's write slot
        if ((k & 3) == 0 && k >= 8 && tid >= 128 && tid < 256) flushY(k - 8);
        __syncthreads();
    };

    // pipeline fill
    interval(sBF,         sBF + PARSZ, 0, true, false, false);
    interval(sBF + PARSZ, sBF,         1, true, true,  false);
    // steady state: k = 2..511, parity-unrolled x2
    for (int k = 2; k < T_LEN; k += 2) {
        interval(sBF,         sBF + PARSZ, k,     true, true, true);
        interval(sBF + PARSZ, sBF,         k + 1, true, true, true);
    }
    // pipeline drain (k=512 even -> reads parity 0)
    interval(sBF,         sBF + PARSZ, T_LEN,     false, true,  true);
    interval(sBF + PARSZ, sBF,         T_LEN + 1, false, false, true);
    // tail flush: t = 508..511 (barrier at end of last interval orders sY)
    if (tid >= 128 && tid < 256) flushY(T_LEN - 4);
}

extern "C" void kernel_launch(void* const* d_in, const int* in_sizes, int n_in,
                              void* d_out, int out_size, void* d_ws, size_t ws_size,
                              hipStream_t stream) {
    const float* x    = (const float*)d_in[0];
    const float* Wih0 = (const float*)d_in[1];
    const float* Whh0 = (const float*)d_in[2];
    const float* bih0 = (const float*)d_in[3];
    const float* bhh0 = (const float*)d_in[4];
    const float* Wih1 = (const float*)d_in[5];
    const float* Whh1 = (const float*)d_in[6];
    const float* bih1 = (const float*)d_in[7];
    const float* bhh1 = (const float*)d_in[8];
    const float* Wih2 = (const float*)d_in[9];
    const float* Whh2 = (const float*)d_in[10];
    const float* bih2 = (const float*)d_in[11];
    const float* bhh2 = (const float*)d_in[12];
    const float* Wout = (const float*)d_in[13];
    const float* bout = (const float*)d_in[14];

    lstm_fused<<<dim3(2048 / BT), dim3(NTH), 0, stream>>>(
        x, Wih0, Whh0, bih0, bhh0, Wih1, Whh1, bih1, bhh1,
        Wih2, Whh2, bih2, bhh2, Wout, bout, (float*)d_out);
}

// Round 11
// 560.821 us; speedup vs baseline: 6.2817x; 1.0089x over previous
//
#include <hip/hip_runtime.h>

#define T_LEN 512
#define HID   40
#define BT    8        // sequences per block -> grid 256 = 1 block/CU
#define NTH   640      // 10 waves; wave w owns units u = 4w..4w+3 (all 4 gates)

typedef _Float16 f16x8 __attribute__((ext_vector_type(8)));
typedef float    f32x4 __attribute__((ext_vector_type(4)));

// B-fragment LDS: one buffer per layer, cols 0-7 = h_hi, cols 8-15 = h_lo.
// Chunked lane-linear layout (chunk = s*64+lane, 16B), parity double-buffered.
#define O_L0  0        // L0 (K-pad 64): 2 K-steps * 512 = 1024
#define O_L1  1024     // L1 (K-pad 96): 3 * 512 = 1536
#define O_L2  2560
#define PARSZ 4096     // fp16 per parity bank (8 KB); 2 banks = 16 KB

#define NLOG2E  (-1.4426950408889634f)   // -log2(e): sigmoid-gate pre-scale
#define N2LOG2E (-2.8853900817779268f)   // -2*log2(e): tanh-gate pre-scale

__device__ __forceinline__ float fast_rcp(float v)  { return __builtin_amdgcn_rcpf(v); }
__device__ __forceinline__ float fast_exp2(float v) { return __builtin_amdgcn_exp2f(v); }

__device__ __forceinline__ float dpp_add_xor1(float x) {
    return x + __int_as_float(__builtin_amdgcn_update_dpp(
                   0, __float_as_int(x), 0xB1, 0xF, 0xF, true));
}
__device__ __forceinline__ float dpp_add_xor2(float x) {
    return x + __int_as_float(__builtin_amdgcn_update_dpp(
                   0, __float_as_int(x), 0x4E, 0xF, 0xF, true));
}
// row_ror:8 — lane n receives lane (n+8)%16 of its 16-lane row. Pure VALU.
__device__ __forceinline__ float dpp_add_ror8(float x) {
    return x + __int_as_float(__builtin_amdgcn_update_dpp(
                   0, __float_as_int(x), 0x128, 0xF, 0xF, true));
}
__device__ __forceinline__ float dpp_mov_ror8(float x) {
    return __int_as_float(__builtin_amdgcn_update_dpp(
               0, __float_as_int(x), 0x128, 0xF, 0xF, true));
}

// element index for (kpos, col): chunk = (k/32)*64 + ((k%32)/8)*16 + col, elem k%8
__device__ __forceinline__ int bidx(int kpos, int col) {
    return (((kpos >> 5) * 64) + (((kpos >> 3) & 3) * 16) + col) * 8 + (kpos & 7);
}

// KF full K-steps (lane-linear b128) + 1 tail step where quads 2,3 carry only
// zero A-elements -> their B read mirrors quads 0,1 (broadcast, half traffic).
template <int KF>
__device__ __forceinline__ f32x4 gemm2t(const _Float16* __restrict__ B,
                                        const f16x8 (&Ah)[KF + 1],
                                        const f16x8 (&Al)[KF + 1],
                                        f32x4 acc, int lOff, int tOff) {
#pragma unroll
    for (int s = 0; s < KF; ++s) {
        f16x8 b = *(const f16x8*)(B + s * 512 + lOff);
        acc = __builtin_amdgcn_mfma_f32_16x16x32_f16(Ah[s], b, acc, 0, 0, 0);
        acc = __builtin_amdgcn_mfma_f32_16x16x32_f16(Al[s], b, acc, 0, 0, 0);
    }
    f16x8 bt = *(const f16x8*)(B + KF * 512 + tOff);
    acc = __builtin_amdgcn_mfma_f32_16x16x32_f16(Ah[KF], bt, acc, 0, 0, 0);
    acc = __builtin_amdgcn_mfma_f32_16x16x32_f16(Al[KF], bt, acc, 0, 0, 0);
    return acc;
}

__global__ __launch_bounds__(NTH, 1) void lstm_fused(
    const float* __restrict__ x,
    const float* __restrict__ Wih0, const float* __restrict__ Whh0,
    const float* __restrict__ bih0, const float* __restrict__ bhh0,
    const float* __restrict__ Wih1, const float* __restrict__ Whh1,
    const float* __restrict__ bih1, const float* __restrict__ bhh1,
    const float* __restrict__ Wih2, const float* __restrict__ Whh2,
    const float* __restrict__ bih2, const float* __restrict__ bhh2,
    const float* __restrict__ Wout, const float* __restrict__ bout,
    float* __restrict__ out) {
    __shared__ __attribute__((aligned(16))) _Float16 sBF[2 * PARSZ];   // 16 KB
    __shared__ __attribute__((aligned(16))) float    sY[8 * HID * BT]; // 10 KB, 8 slots

    const int  tid  = threadIdx.x;
    const int  lane = tid & 63;
    const int  w    = tid >> 6;       // wave id = u-tile
    const int  n    = lane & 15;      // B/D column (seq b when n<8; n>=8 = lo-half)
    const int  quad = lane >> 4;
    const int  u    = w * 4 + quad;   // hidden unit this lane owns (cell update)
    const int  seq0 = blockIdx.x * BT;
    const bool hiL  = (n < 8);        // hi-half lane?

    // read offsets (elems): main = lane-linear; tail = quads 2,3 mirror 0,1
    const int lOff = lane * 8;
    const int tOff = (((quad & 1) * 16) + n) * 8;

    // ---- A-fragments: gate-permuted rows, split fp16, PRE-SCALED so all
    // activations become rcp(1+exp2(acc)): sigmoid rows x(-log2e), tanh rows
    // x(-2log2e). tile row r -> gate j = (r%4)*40 + w*4 + r/4.
    const int   ja  = (n & 3) * 40 + w * 4 + (n >> 2);
    const float sca = ((n & 3) == 2) ? N2LOG2E : NLOG2E;
    f16x8 A0h[2], A0l[2], A1h[3], A1l[3], A2h[3], A2l[3];
#pragma unroll
    for (int s = 0; s < 2; ++s)
#pragma unroll
        for (int jj = 0; jj < 8; ++jj) {
            int   k = s * 32 + quad * 8 + jj;
            float v = (k < 6) ? Wih0[ja * 6 + k] : (k < 46) ? Whh0[ja * 40 + (k - 6)] : 0.f;
            v *= sca;
            _Float16 hi = (_Float16)v;
            A0h[s][jj] = hi;
            A0l[s][jj] = (_Float16)(v - (float)hi);
        }
#pragma unroll
    for (int s = 0; s < 3; ++s)
#pragma unroll
        for (int jj = 0; jj < 8; ++jj) {
            int   k  = s * 32 + quad * 8 + jj;
            float v1 = (k < 40) ? Wih1[ja * 40 + k] : (k < 80) ? Whh1[ja * 40 + (k - 40)] : 0.f;
            float v2 = (k < 40) ? Wih2[ja * 40 + k] : (k < 80) ? Whh2[ja * 40 + (k - 40)] : 0.f;
            v1 *= sca; v2 *= sca;
            _Float16 h1 = (_Float16)v1, h2 = (_Float16)v2;
            A1h[s][jj] = h1; A1l[s][jj] = (_Float16)(v1 - (float)h1);
            A2h[s][jj] = h2; A2l[s][jj] = (_Float16)(v2 - (float)h2);
        }

    // biases: acc-init = 0.5*scale*bias (0.5 exact; hi+lo col fold restores 1x)
    f32x4 bia0, bia1, bia2;
#pragma unroll
    for (int reg = 0; reg < 4; ++reg) {
        int   jr = reg * 40 + u;
        float sc = 0.5f * ((reg == 2) ? N2LOG2E : NLOG2E);
        bia0[reg] = sc * (bih0[jr] + bhh0[jr]);
        bia1[reg] = sc * (bih1[jr] + bhh1[jr]);
        bia2[reg] = sc * (bih2[jr] + bhh2[jr]);
    }
    const float wov   = Wout[u];
    const float boutv = bout[0];

    float c0 = 0.f, c1 = 0.f, c2 = 0.f;  // cell states (duplicated on lane pair)

    // ---- loop-invariant LDS write indices: lane's own column (hi or lo) ----
    const int iU  = bidx(6 + u, n);   // L0 h-slot
    const int iIN = bidx(u, n);       // L1/L2 input slot
    const int iH  = bidx(40 + u, n);  // L1/L2 h-slot

    // ---- x staging on waves 2,3 (SIMDs 2,3 = the 2-compute-wave SIMDs) ----
    const bool   xact = (tid >= 128 && tid < 224);
    const int    e    = tid - 128;
    const int    xs   = e / 12, xrr = e % 12;
    const int    xd   = xrr % 6, xhalf = xrr / 6;
    const int    ixi  = bidx(xd, xs + xhalf * 8);
    const float* xbl  = x + ((size_t)(seq0 + xs) * T_LEN) * 6 + xd;
    float        xr   = 0.f;
    if (xact) xr = xbl[0];  // x(0)

    // zero both parity banks (K-pads stay zero forever)
    for (int i = tid; i < 2 * PARSZ / 8; i += NTH)
        *(float4*)&sBF[i * 8] = make_float4(0.f, 0.f, 0.f, 0.f);
    __syncthreads();
    if (xact) {
        _Float16 hi = (_Float16)xr;
        sBF[O_L0 + ixi] = xhalf ? (_Float16)(xr - (float)hi) : hi;  // x(0) -> parity 0
        xr = xbl[6];                                                 // prefetch x(1)
    }
    __syncthreads();

    // stage1: fold hi/lo cols, split gate trans across the lane pair, exchange.
    auto stage1 = [&](f32x4 acc, float& ig, float& fs, float& os) {
        float g0 = dpp_add_ror8(acc[0]);   // i
        float g1 = dpp_add_ror8(acc[1]);   // f
        float g2 = dpp_add_ror8(acc[2]);   // g (pre-scaled 2x)
        float g3 = dpp_add_ror8(acc[3]);   // o
        float in0 = hiL ? g0 : g2;
        float in1 = hiL ? g1 : g3;
        float e0  = fast_rcp(1.f + fast_exp2(in0));
        float v0  = hiL ? e0 : (2.f * e0 - 1.f);   // hi: sig(i)  lo: tanh(g)
        float v1  = fast_rcp(1.f + fast_exp2(in1)); // hi: sig(f)  lo: sig(o)
        float r0  = dpp_mov_ror8(v0);
        float r1  = dpp_mov_ror8(v1);
        ig = v0 * r0;                               // sig(i)*tanh(g) on both
        fs = hiL ? v1 : r1;
        os = hiL ? r1 : v1;
    };
    auto packval = [&](float h) -> _Float16 {
        _Float16 hi = (_Float16)h;
        _Float16 lo = (_Float16)(h - (float)hi);
        return hiL ? hi : lo;
    };

    // lagged output flush on waves 2,3: group of 4 timesteps ending at t2g+3
    auto flushY = [&](int t2g) {
        int q = tid - 128, o = q >> 2, part = q & 3;
        int tt = o >> 3, bb = o & 7;
        int slot = (t2g + tt) & 7;
        float s = 0.f;
#pragma unroll
        for (int i2 = 0; i2 < 10; ++i2)
            s += sY[slot * (HID * BT) + (part * 10 + i2) * BT + bb];
        s = dpp_add_xor1(s);
        s = dpp_add_xor2(s);
        if (part == 0)
            out[(size_t)(seq0 + bb) * T_LEN + t2g + tt] = s + boutv;
    };

    // One pipeline interval k: L0(t=k), L1(t=k-1), L2(t=k-2). Reads P, writes Q,
    // ONE barrier. The three gemm/activation chains are independent -> 3x ILP.
    auto interval = [&](_Float16* __restrict__ P, _Float16* __restrict__ Q,
                        int k, bool a0, bool a1, bool a2) {
        f32x4 acc0, acc1, acc2;
        if (a0) acc0 = gemm2t<1>(P + O_L0, A0h, A0l, bia0, lOff, tOff);
        if (a1) acc1 = gemm2t<2>(P + O_L1, A1h, A1l, bia1, lOff, tOff);
        if (a2) acc2 = gemm2t<2>(P + O_L2, A2h, A2l, bia2, lOff, tOff);

        float ig0, fs0, os0, ig1, fs1, os1, ig2, fs2, os2;
        if (a0) { stage1(acc0, ig0, fs0, os0); c0 = fs0 * c0 + ig0; }
        if (a1) { stage1(acc1, ig1, fs1, os1); c1 = fs1 * c1 + ig1; }
        if (a2) { stage1(acc2, ig2, fs2, os2); c2 = fs2 * c2 + ig2; }

        // packed th: hi lanes compute tanh(c0), lo lanes tanh(c1), exchange
        float inC = hiL ? c0 : c1;
        float thA = 2.f * fast_rcp(1.f + fast_exp2(inC * N2LOG2E)) - 1.f;
        float thB = dpp_mov_ror8(thA);
        float th0 = hiL ? thA : thB;
        float th1 = hiL ? thB : thA;
        float th2 = 2.f * fast_rcp(1.f + fast_exp2(c2 * N2LOG2E)) - 1.f;

        if (a0) {
            float h = os0 * th0;
            _Float16 v = packval(h);
            Q[O_L0 + iU]  = v;
            Q[O_L1 + iIN] = v;
        }
        if (a1) {
            float h = os1 * th1;
            _Float16 v = packval(h);
            Q[O_L1 + iH]  = v;
            Q[O_L2 + iIN] = v;
        }
        if (a2) {
            float h = os2 * th2;
            _Float16 v = packval(h);
            Q[O_L2 + iH] = v;
            if (hiL) sY[((k - 2) & 7) * (HID * BT) + u * BT + n] = h * wov;
        }
        if (xact) {   // stage x(k+1); clamped load, harmless past-end store
            _Float16 hi = (_Float16)xr;
            Q[O_L0 + ixi] = xhalf ? (_Float16)(xr - (float)hi) : hi;
            int kc = (k + 2 < T_LEN) ? (k + 2) : (T_LEN - 1);
            xr = xbl[(size_t)kc * 6];
        }
        // flush group (k-8..k-5): slots disjoint from this interval's write slot
        if ((k & 3) == 0 && k >= 8 && tid >= 128 && tid < 256) flushY(k - 8);
        __syncthreads();
    };

    // pipeline fill
    interval(sBF,         sBF + PARSZ, 0, true, false, false);
    interval(sBF + PARSZ, sBF,         1, true, true,  false);
    // steady state: k = 2..511, parity-unrolled x2
    for (int k = 2; k < T_LEN; k += 2) {
        interval(sBF,         sBF + PARSZ, k,     true, true, true);
        interval(sBF + PARSZ, sBF,         k + 1, true, true, true);
    }
    // pipeline drain (k=512 even -> reads parity 0)
    interval(sBF,         sBF + PARSZ, T_LEN,     false, true,  true);
    interval(sBF + PARSZ, sBF,         T_LEN + 1, false, false, true);
    // tail flush: t = 508..511 (barrier at end of last interval orders sY)
    if (tid >= 128 && tid < 256) flushY(T_LEN - 4);
}

extern "C" void kernel_launch(void* const* d_in, const int* in_sizes, int n_in,
                              void* d_out, int out_size, void* d_ws, size_t ws_size,
                              hipStream_t stream) {
    const float* x    = (const float*)d_in[0];
    const float* Wih0 = (const float*)d_in[1];
    const float* Whh0 = (const float*)d_in[2];
    const float* bih0 = (const float*)d_in[3];
    const float* bhh0 = (const float*)d_in[4];
    const float* Wih1 = (const float*)d_in[5];
    const float* Whh1 = (const float*)d_in[6];
    const float* bih1 = (const float*)d_in[7];
    const float* bhh1 = (const float*)d_in[8];
    const float* Wih2 = (const float*)d_in[9];
    const float* Whh2 = (const float*)d_in[10];
    const float* bih2 = (const float*)d_in[11];
    const float* bhh2 = (const float*)d_in[12];
    const float* Wout = (const float*)d_in[13];
    const float* bout = (const float*)d_in[14];

    lstm_fused<<<dim3(2048 / BT), dim3(NTH), 0, stream>>>(
        x, Wih0, Whh0, bih0, bhh0, Wih1, Whh1, bih1, bhh1,
        Wih2, Whh2, bih2, bhh2, Wout, bout, (float*)d_out);
}

// Round 12
// 560.725 us; speedup vs baseline: 6.2828x; 1.0002x over previous
//
#include <hip/hip_runtime.h>

#define T_LEN 512
#define HID   40
#define BT    8        // sequences per block -> grid 256 = 1 block/CU
#define NTH   640      // 10 waves; wave w owns units u = 4w..4w+3 (all 4 gates)

typedef _Float16 f16x8 __attribute__((ext_vector_type(8)));
typedef float    f32x4 __attribute__((ext_vector_type(4)));

// Unified B-buffer per parity: ONE chunked K-axis [h0(gk0..39)|h1(40..79)|
// h2(80..119)|x(120..125)|pad(..135)] = 272 chunks. cols 0-7 = hi, 8-15 = lo.
// All three gemms read phase-aligned 64-chunk windows r0..r3 (4 reads total);
// A-fragments are zero outside each gemm's K-support (exact).
#define PARSZ 2176     // fp16 per parity (272 chunks * 8); 2 parities = 8.5 KB

#define NLOG2E  (-1.4426950408889634f)   // -log2(e): sigmoid-gate pre-scale
#define N2LOG2E (-2.8853900817779268f)   // -2*log2(e): tanh-gate pre-scale

__device__ __forceinline__ float fast_rcp(float v)  { return __builtin_amdgcn_rcpf(v); }
__device__ __forceinline__ float fast_exp2(float v) { return __builtin_amdgcn_exp2f(v); }

__device__ __forceinline__ float dpp_add_xor1(float x) {
    return x + __int_as_float(__builtin_amdgcn_update_dpp(
                   0, __float_as_int(x), 0xB1, 0xF, 0xF, true));
}
__device__ __forceinline__ float dpp_add_xor2(float x) {
    return x + __int_as_float(__builtin_amdgcn_update_dpp(
                   0, __float_as_int(x), 0x4E, 0xF, 0xF, true));
}
// row_ror:8 — lane n receives lane (n+8)%16 of its 16-lane row. Pure VALU.
__device__ __forceinline__ float dpp_add_ror8(float x) {
    return x + __int_as_float(__builtin_amdgcn_update_dpp(
                   0, __float_as_int(x), 0x128, 0xF, 0xF, true));
}
__device__ __forceinline__ float dpp_mov_ror8(float x) {
    return __int_as_float(__builtin_amdgcn_update_dpp(
               0, __float_as_int(x), 0x128, 0xF, 0xF, true));
}

// element index for (global-k, col): chunk = (gk/32)*64 + ((gk%32)/8)*16 + col
__device__ __forceinline__ int bidx(int gk, int col) {
    return (((gk >> 5) * 64) + (((gk >> 3) & 3) * 16) + col) * 8 + (gk & 7);
}

#define MFMA16(A, B, C) __builtin_amdgcn_mfma_f32_16x16x32_f16((A), (B), (C), 0, 0, 0)

__global__ __launch_bounds__(NTH, 1) void lstm_fused(
    const float* __restrict__ x,
    const float* __restrict__ Wih0, const float* __restrict__ Whh0,
    const float* __restrict__ bih0, const float* __restrict__ bhh0,
    const float* __restrict__ Wih1, const float* __restrict__ Whh1,
    const float* __restrict__ bih1, const float* __restrict__ bhh1,
    const float* __restrict__ Wih2, const float* __restrict__ Whh2,
    const float* __restrict__ bih2, const float* __restrict__ bhh2,
    const float* __restrict__ Wout, const float* __restrict__ bout,
    float* __restrict__ out) {
    __shared__ __attribute__((aligned(16))) _Float16 sBF[2 * PARSZ];   // 8.5 KB
    __shared__ __attribute__((aligned(16))) float    sY[8 * HID * BT]; // 10 KB

    const int  tid  = threadIdx.x;
    const int  lane = tid & 63;
    const int  w    = tid >> 6;       // wave id = u-tile
    const int  n    = lane & 15;      // B/D column (seq b when n<8; n>=8 = lo-half)
    const int  quad = lane >> 4;
    const int  u    = w * 4 + quad;   // hidden unit this lane owns (cell update)
    const int  seq0 = blockIdx.x * BT;
    const bool hiL  = (n < 8);        // hi-half lane?

    // ---- A-fragments: gate-permuted rows (j = (r%4)*40 + w*4 + r/4), split
    // fp16, pre-scaled (sigmoid x -log2e, tanh x -2log2e). One frag pair per
    // (gemm, shared-read window): L0 uses {r0,r1,r3}, L1 {r0,r1,r2}, L2 {r1,r2,r3}.
    const int   ja  = (n & 3) * 40 + w * 4 + (n >> 2);
    const float sca = ((n & 3) == 2) ? N2LOG2E : NLOG2E;
    f16x8 F0h[3], F0l[3], F1h[3], F1l[3], F2h[3], F2l[3];
#pragma unroll
    for (int jj = 0; jj < 8; ++jj) {
        int gk0 = quad * 8 + jj;        // r0 window: gk 0..31
        int gk1 = 32 + gk0;             // r1: gk 32..63
        int gk2 = 64 + gk0;             // r2: gk 64..95
        int gk3 = 96 + gk0;             // r3: gk 96..127
        float v;
        // L0 = Whh0*h0 + Wih0*x : support gk 0..39 (h0) and 120..125 (x)
        v = Whh0[ja * 40 + gk0] * sca;
        { _Float16 h = (_Float16)v; F0h[0][jj] = h; F0l[0][jj] = (_Float16)(v - (float)h); }
        v = (gk1 < 40) ? Whh0[ja * 40 + gk1] * sca : 0.f;
        { _Float16 h = (_Float16)v; F0h[1][jj] = h; F0l[1][jj] = (_Float16)(v - (float)h); }
        v = (gk3 >= 120 && gk3 < 126) ? Wih0[ja * 6 + (gk3 - 120)] * sca : 0.f;
        { _Float16 h = (_Float16)v; F0h[2][jj] = h; F0l[2][jj] = (_Float16)(v - (float)h); }
        // L1 = Wih1*h0 + Whh1*h1 : support gk 0..79
        v = Wih1[ja * 40 + gk0] * sca;
        { _Float16 h = (_Float16)v; F1h[0][jj] = h; F1l[0][jj] = (_Float16)(v - (float)h); }
        v = ((gk1 < 40) ? Wih1[ja * 40 + gk1] : Whh1[ja * 40 + (gk1 - 40)]) * sca;
        { _Float16 h = (_Float16)v; F1h[1][jj] = h; F1l[1][jj] = (_Float16)(v - (float)h); }
        v = (gk2 < 80) ? Whh1[ja * 40 + (gk2 - 40)] * sca : 0.f;
        { _Float16 h = (_Float16)v; F1h[2][jj] = h; F1l[2][jj] = (_Float16)(v - (float)h); }
        // L2 = Wih2*h1 + Whh2*h2 : support gk 40..119
        v = (gk1 >= 40) ? Wih2[ja * 40 + (gk1 - 40)] * sca : 0.f;
        { _Float16 h = (_Float16)v; F2h[0][jj] = h; F2l[0][jj] = (_Float16)(v - (float)h); }
        v = ((gk2 < 80) ? Wih2[ja * 40 + (gk2 - 40)] : Whh2[ja * 40 + (gk2 - 80)]) * sca;
        { _Float16 h = (_Float16)v; F2h[1][jj] = h; F2l[1][jj] = (_Float16)(v - (float)h); }
        v = (gk3 < 120) ? Whh2[ja * 40 + (gk3 - 80)] * sca : 0.f;
        { _Float16 h = (_Float16)v; F2h[2][jj] = h; F2l[2][jj] = (_Float16)(v - (float)h); }
    }

    // biases: acc-init = 0.5*scale*bias (0.5 exact; hi+lo col fold restores 1x)
    f32x4 bia0, bia1, bia2;
#pragma unroll
    for (int reg = 0; reg < 4; ++reg) {
        int   jr = reg * 40 + u;
        float sc = 0.5f * ((reg == 2) ? N2LOG2E : NLOG2E);
        bia0[reg] = sc * (bih0[jr] + bhh0[jr]);
        bia1[reg] = sc * (bih1[jr] + bhh1[jr]);
        bia2[reg] = sc * (bih2[jr] + bhh2[jr]);
    }
    const float wov   = Wout[u];
    const float boutv = bout[0];

    float c0 = 0.f, c1 = 0.f, c2 = 0.f;  // cell states (duplicated on lane pair)

    // ---- loop-invariant LDS indices (elems) ----
    const int rOff = lane * 8;           // shared-window read offset
    const int iH0  = bidx(u, n);         // h0 write (single destination now)
    const int iH1  = bidx(40 + u, n);    // h1
    const int iH2  = bidx(80 + u, n);    // h2

    // ---- x staging on waves 2,3 ----
    const bool   xact = (tid >= 128 && tid < 224);
    const int    e    = tid - 128;
    const int    xs   = e / 12, xrr = e % 12;
    const int    xd   = xrr % 6, xhalf = xrr / 6;
    const int    ixi  = bidx(120 + xd, xs + xhalf * 8);
    const float* xbl  = x + ((size_t)(seq0 + xs) * T_LEN) * 6 + xd;
    float        xr   = 0.f;
    if (xact) xr = xbl[0];  // x(0)

    // zero both parity banks (pads + unwritten regions stay zero)
    for (int i = tid; i < 2 * PARSZ / 8; i += NTH)
        *(float4*)&sBF[i * 8] = make_float4(0.f, 0.f, 0.f, 0.f);
    __syncthreads();
    if (xact) {
        _Float16 hi = (_Float16)xr;
        sBF[ixi] = xhalf ? (_Float16)(xr - (float)hi) : hi;  // x(0) -> parity 0
        xr = xbl[6];                                          // prefetch x(1)
    }
    __syncthreads();

    // stage1: fold hi/lo cols, split gate trans across the lane pair, exchange.
    auto stage1 = [&](f32x4 acc, float& ig, float& fs, float& os) {
        float g0 = dpp_add_ror8(acc[0]);   // i
        float g1 = dpp_add_ror8(acc[1]);   // f
        float g2 = dpp_add_ror8(acc[2]);   // g (pre-scaled 2x)
        float g3 = dpp_add_ror8(acc[3]);   // o
        float in0 = hiL ? g0 : g2;
        float in1 = hiL ? g1 : g3;
        float e0  = fast_rcp(1.f + fast_exp2(in0));
        float v0  = hiL ? e0 : (2.f * e0 - 1.f);    // hi: sig(i)  lo: tanh(g)
        float v1  = fast_rcp(1.f + fast_exp2(in1)); // hi: sig(f)  lo: sig(o)
        float r0  = dpp_mov_ror8(v0);
        float r1  = dpp_mov_ror8(v1);
        ig = v0 * r0;                               // sig(i)*tanh(g) on both
        fs = hiL ? v1 : r1;
        os = hiL ? r1 : v1;
    };
    auto packval = [&](float h) -> _Float16 {
        _Float16 hi = (_Float16)h;
        _Float16 lo = (_Float16)(h - (float)hi);
        return hiL ? hi : lo;
    };

    // lagged output flush on waves 2,3: group of 4 timesteps ending at t2g+3
    auto flushY = [&](int t2g) {
        int q = tid - 128, o = q >> 2, part = q & 3;
        int tt = o >> 3, bb = o & 7;
        int slot = (t2g + tt) & 7;
        float s = 0.f;
#pragma unroll
        for (int i2 = 0; i2 < 10; ++i2)
            s += sY[slot * (HID * BT) + (part * 10 + i2) * BT + bb];
        s = dpp_add_xor1(s);
        s = dpp_add_xor2(s);
        if (part == 0)
            out[(size_t)(seq0 + bb) * T_LEN + t2g + tt] = s + boutv;
    };

    // One pipeline interval k: L0(t=k), L1(t=k-1), L2(t=k-2). Reads P, writes Q,
    // ONE barrier. 4 shared b128 reads feed all three gemm chains (3x ILP).
    auto interval = [&](_Float16* __restrict__ P, _Float16* __restrict__ Q,
                        int k, bool a0, bool a1, bool a2) {
        f16x8 b0 = *(const f16x8*)(P + 0    + rOff);
        f16x8 b1 = *(const f16x8*)(P + 512  + rOff);
        f16x8 b2 = *(const f16x8*)(P + 1024 + rOff);
        f16x8 b3 = *(const f16x8*)(P + 1536 + rOff);

        f32x4 acc0, acc1, acc2;
        if (a0) {
            acc0 = MFMA16(F0h[0], b0, bia0); acc0 = MFMA16(F0l[0], b0, acc0);
            acc0 = MFMA16(F0h[1], b1, acc0); acc0 = MFMA16(F0l[1], b1, acc0);
            acc0 = MFMA16(F0h[2], b3, acc0); acc0 = MFMA16(F0l[2], b3, acc0);
        }
        if (a1) {
            acc1 = MFMA16(F1h[0], b0, bia1); acc1 = MFMA16(F1l[0], b0, acc1);
            acc1 = MFMA16(F1h[1], b1, acc1); acc1 = MFMA16(F1l[1], b1, acc1);
            acc1 = MFMA16(F1h[2], b2, acc1); acc1 = MFMA16(F1l[2], b2, acc1);
        }
        if (a2) {
            acc2 = MFMA16(F2h[0], b1, bia2); acc2 = MFMA16(F2l[0], b1, acc2);
            acc2 = MFMA16(F2h[1], b2, acc2); acc2 = MFMA16(F2l[1], b2, acc2);
            acc2 = MFMA16(F2h[2], b3, acc2); acc2 = MFMA16(F2l[2], b3, acc2);
        }

        float ig0, fs0, os0, ig1, fs1, os1, ig2, fs2, os2;
        if (a0) { stage1(acc0, ig0, fs0, os0); c0 = fs0 * c0 + ig0; }
        if (a1) { stage1(acc1, ig1, fs1, os1); c1 = fs1 * c1 + ig1; }
        if (a2) { stage1(acc2, ig2, fs2, os2); c2 = fs2 * c2 + ig2; }

        // packed th: hi lanes compute tanh(c0), lo lanes tanh(c1), exchange
        float inC = hiL ? c0 : c1;
        float thA = 2.f * fast_rcp(1.f + fast_exp2(inC * N2LOG2E)) - 1.f;
        float thB = dpp_mov_ror8(thA);
        float th0 = hiL ? thA : thB;
        float th1 = hiL ? thB : thA;
        float th2 = 2.f * fast_rcp(1.f + fast_exp2(c2 * N2LOG2E)) - 1.f;

        if (a0) Q[iH0] = packval(os0 * th0);   // single write: L1 reads it here too
        if (a1) Q[iH1] = packval(os1 * th1);
        if (a2) {
            float h = os2 * th2;
            Q[iH2] = packval(h);
            if (hiL) sY[((k - 2) & 7) * (HID * BT) + u * BT + n] = h * wov;
        }
        if (xact) {   // stage x(k+1); clamped load, harmless past-end store
            _Float16 hi = (_Float16)xr;
            Q[ixi] = xhalf ? (_Float16)(xr - (float)hi) : hi;
            int kc = (k + 2 < T_LEN) ? (k + 2) : (T_LEN - 1);
            xr = xbl[(size_t)kc * 6];
        }
        // flush group (k-8..k-5): slots disjoint from this interval's write slot
        if ((k & 3) == 0 && k >= 8 && tid >= 128 && tid < 256) flushY(k - 8);
        __syncthreads();
    };

    // pipeline fill
    interval(sBF,         sBF + PARSZ, 0, true, false, false);
    interval(sBF + PARSZ, sBF,         1, true, true,  false);
    // steady state: k = 2..511, parity-unrolled x2
    for (int k = 2; k < T_LEN; k += 2) {
        interval(sBF,         sBF + PARSZ, k,     true, true, true);
        interval(sBF + PARSZ, sBF,         k + 1, true, true, true);
    }
    // pipeline drain (k=512 even -> reads parity 0)
    interval(sBF,         sBF + PARSZ, T_LEN,     false, true,  true);
    interval(sBF + PARSZ, sBF,         T_LEN + 1, false, false, true);
    // tail flush: t = 508..511 (barrier at end of last interval orders sY)
    if (tid >= 128 && tid < 256) flushY(T_LEN - 4);
}

extern "C" void kernel_launch(void* const* d_in, const int* in_sizes, int n_in,
                              void* d_out, int out_size, void* d_ws, size_t ws_size,
                              hipStream_t stream) {
    const float* x    = (const float*)d_in[0];
    const float* Wih0 = (const float*)d_in[1];
    const float* Whh0 = (const float*)d_in[2];
    const float* bih0 = (const float*)d_in[3];
    const float* bhh0 = (const float*)d_in[4];
    const float* Wih1 = (const float*)d_in[5];
    const float* Whh1 = (const float*)d_in[6];
    const float* bih1 = (const float*)d_in[7];
    const float* bhh1 = (const float*)d_in[8];
    const float* Wih2 = (const float*)d_in[9];
    const float* Whh2 = (const float*)d_in[10];
    const float* bih2 = (const float*)d_in[11];
    const float* bhh2 = (const float*)d_in[12];
    const float* Wout = (const float*)d_in[13];
    const float* bout = (const float*)d_in[14];

    lstm_fused<<<dim3(2048 / BT), dim3(NTH), 0, stream>>>(
        x, Wih0, Whh0, bih0, bhh0, Wih1, Whh1, bih1, bhh1,
        Wih2, Whh2, bih2, bhh2, Wout, bout, (float*)d_out);
}